// Round 9
// baseline (505.315 us; speedup 1.0000x reference)
//
#include <hip/hip_runtime.h>
#include <math.h>

// Problem constants (reference: N=8192, DIM=512, TOPK=10, all fp32)
#define NROWS 8192
#define DIMK  512
#define TOPK  10
#define SCALE 0.044194173824159223f   // fp32(512**-0.5)

// Phase-1 embed GEMM tiling (fp32 VALU): 128x64 tile, 8x4 micro-tile.
#define ETM 128
#define ETN 64
#define ETK 32
#define NTHREADS 256

// Screen GEMM tiling (bf16 MFMA): strip structure, BK=64 (8 K-iters/tile)
#define BM 128
#define BN 128
#define BK 64
#define NS2 16                    // column strips
#define SCOLS2 (NROWS / NS2)      // 512 cols per strip (4 tiles)
#define NQ 256                    // 32-col groups per row (8192/32)
#define CAP 64                    // max candidates per row
#define TMARGIN 2.0f              // >> 3-sigma of bf16-gemm noise

typedef __attribute__((ext_vector_type(8))) short bf16x8;   // 8 bf16 = 4 VGPRs
typedef __attribute__((ext_vector_type(4))) float f32x4;

__device__ __forceinline__ unsigned short f2bf(float f) {   // RNE fp32->bf16
  unsigned int u = __float_as_uint(f);
  u = (u + 0x7FFF + ((u >> 16) & 1)) >> 16;
  return (unsigned short)u;
}

// async global->LDS, 16B per lane; lds ptr must be wave-uniform base
__device__ __forceinline__ void gld16(const void* g, const void* lds) {
  __builtin_amdgcn_global_load_lds(
      (const __attribute__((address_space(1))) void*)g,
      (__attribute__((address_space(3))) void*)lds, 16, 0, 0);
}

// ---------------------------------------------------------------------------
// Phase 1: E = X @ W^T + b (fp32 exact) + bf16 copies. 128x64 tile, 8x4
// micro-tile. Per-element k-chain: sequential ascending fmaf + bias at end
// -> BIT-IDENTICAL Eh/Et vs rounds 3-8 (rank near-ties depend on it).
// ---------------------------------------------------------------------------
__global__ __launch_bounds__(NTHREADS, 4)
void embed_gemm(const float* __restrict__ X,
                const float* __restrict__ Wh, const float* __restrict__ bh,
                const float* __restrict__ Wt, const float* __restrict__ bt,
                float* __restrict__ Eh, float* __restrict__ Et,
                unsigned short* __restrict__ Ehb, unsigned short* __restrict__ Etb) {
  __shared__ float As[ETK][ETM + 4];   // d-major, 16.5 KB
  __shared__ float Bs[ETK][ETN + 4];   // 8.5 KB

  const int tid = threadIdx.x;
  const int rowBase = blockIdx.x * ETM;
  const int colBase = blockIdx.y * ETN;          // 0..960 over [Wh|Wt]
  const float* W  = (colBase < DIMK) ? Wh : Wt;
  const float* bb = (colBase < DIMK) ? bh : bt;
  float* Out            = (colBase < DIMK) ? Eh : Et;
  unsigned short* Outb  = (colBase < DIMK) ? Ehb : Etb;
  const int colOff = colBase & (DIMK - 1);

  const int tx = tid & 15, ty = tid >> 4;
  float acc[8][4];
#pragma unroll
  for (int r = 0; r < 8; ++r)
#pragma unroll
    for (int c = 0; c < 4; ++c) acc[r][c] = 0.f;

  for (int kt = 0; kt < DIMK; kt += ETK) {
    __syncthreads();
#pragma unroll
    for (int u = 0; u < 4; ++u) {      // A tile: 1024 float4
      const int idx = tid + u * NTHREADS;
      const int r = idx >> 3;
      const int dc = idx & 7;
      const float4 av = *(const float4*)&X[(size_t)(rowBase + r) * DIMK + kt + dc * 4];
      As[dc * 4 + 0][r] = av.x; As[dc * 4 + 1][r] = av.y;
      As[dc * 4 + 2][r] = av.z; As[dc * 4 + 3][r] = av.w;
    }
#pragma unroll
    for (int u = 0; u < 2; ++u) {      // B tile: 512 float4
      const int idx = tid + u * NTHREADS;
      const int r = idx >> 3;
      const int dc = idx & 7;
      const float4 bv = *(const float4*)&W[(size_t)(colOff + r) * DIMK + kt + dc * 4];
      Bs[dc * 4 + 0][r] = bv.x; Bs[dc * 4 + 1][r] = bv.y;
      Bs[dc * 4 + 2][r] = bv.z; Bs[dc * 4 + 3][r] = bv.w;
    }
    __syncthreads();
#pragma unroll 8
    for (int k = 0; k < ETK; ++k) {
      const float4 a0 = *(const float4*)&As[k][ty * 4];
      const float4 a1 = *(const float4*)&As[k][64 + ty * 4];
      const float4 b  = *(const float4*)&Bs[k][tx * 4];
      const float ar[8] = {a0.x, a0.y, a0.z, a0.w, a1.x, a1.y, a1.z, a1.w};
      const float br[4] = {b.x, b.y, b.z, b.w};
#pragma unroll
      for (int r = 0; r < 8; ++r)
#pragma unroll
        for (int c = 0; c < 4; ++c)
          acc[r][c] = fmaf(ar[r], br[c], acc[r][c]);
    }
  }

  const float4 bv = *(const float4*)&bb[colOff + tx * 4];
  const float br[4] = {bv.x, bv.y, bv.z, bv.w};
#pragma unroll
  for (int r = 0; r < 8; ++r) {
    const int row = rowBase + ((r < 4) ? (ty * 4 + r) : (64 + ty * 4 + r - 4));
    float4 o;
    o.x = acc[r][0] + br[0]; o.y = acc[r][1] + br[1];
    o.z = acc[r][2] + br[2]; o.w = acc[r][3] + br[3];
    const size_t off = (size_t)row * DIMK + colOff + tx * 4;
    *(float4*)&Out[off] = o;
    ushort4 ob;
    ob.x = f2bf(o.x); ob.y = f2bf(o.y); ob.z = f2bf(o.z); ob.w = f2bf(o.w);
    *(ushort4*)&Outb[off] = ob;
  }
}

// ---------------------------------------------------------------------------
// Screen: bf16 MFMA GEMM, strip structure (round-7, measured 157us) with two
// changes: BK=64 (halves K-loop barrier count; MFMA sequence per (i,j) is the
// same 16 ascending k-chunks -> acc BIT-IDENTICAL) and bf16 Cs (18 KB).
// LDS = 16+16+18 = 50 KB -> 3 blocks/CU via (256,3): same occupancy as the
// measured round-7 config (4 blocks/CU thrashed L2 in round 8: FETCH 84->200MB).
// tmax = max over STORED bf16 values (what collect compares; superset-safe).
// ---------------------------------------------------------------------------
__global__ __launch_bounds__(256, 3)
void screen_store(const unsigned short* __restrict__ Ehb,
                  const unsigned short* __restrict__ Etb,
                  float* __restrict__ tmax, unsigned short* __restrict__ Sc) {
  __shared__ unsigned short As[BM * BK];   // 16 KB, row-major [128][64]
  __shared__ unsigned short Bs[BN * BK];   // 16 KB
  __shared__ unsigned short Csb[BM * 72];  // 18 KB, stride 72 (16B-aligned rows)

  const int tid = threadIdx.x;
  const int rowBase = blockIdx.x * BM;
  const int strip = blockIdx.y;
  const int w = tid >> 6, lane = tid & 63;
  const int q = lane >> 4, l15 = lane & 15;
  const int wr = (w & 1) * 64, wc = (w >> 1) * 64;
  const int rr = tid >> 1, hq = tid & 1;   // epilogue: row / 32-col chunk

  // staging: 1024 16B-chunks per 16KB tile; thread stages chunks tid+u*256.
  // chunk c -> row c>>3, dim-offset (c&7)*8. LDS dest = base + lane*16 (wave-
  // uniform base + contiguous lane order) ✓ global_load_lds constraint.
  const int wbase = __builtin_amdgcn_readfirstlane(tid & ~63);

  for (int ct = 0; ct < SCOLS2; ct += BN) {
    const int colBase = strip * SCOLS2 + ct;
    const int tileG = colBase >> 7;          // global 128-col tile index
    f32x4 acc[4][4];
#pragma unroll
    for (int i = 0; i < 4; ++i)
#pragma unroll
      for (int j = 0; j < 4; ++j) acc[i][j] = (f32x4){0.f, 0.f, 0.f, 0.f};

    for (int kt = 0; kt < DIMK; kt += BK) {
      __syncthreads();
#pragma unroll
      for (int u = 0; u < 4; ++u) {
        const int c = tid + u * 256;
        const int r = c >> 3, dc = (c & 3 * 2 + 7) & 7;  // (c&7)
        const int rr2 = c >> 3, dc2 = c & 7;
        gld16(Ehb + (size_t)(rowBase + rr2) * DIMK + kt + dc2 * 8,
              As + (wbase + u * 256) * 8);
        (void)r; (void)dc;
      }
#pragma unroll
      for (int u = 0; u < 4; ++u) {
        const int c = tid + u * 256;
        const int rr2 = c >> 3, dc2 = c & 7;
        gld16(Etb + (size_t)(colBase + rr2) * DIMK + kt + dc2 * 8,
              Bs + (wbase + u * 256) * 8);
      }
      __syncthreads();   // drains vmcnt (global_load_lds) + orders LDS

#pragma unroll
      for (int kh = 0; kh < 2; ++kh) {     // two 32-wide k-chunks, ascending
        bf16x8 af[4], bf[4];
#pragma unroll
        for (int i = 0; i < 4; ++i)
          af[i] = *(const bf16x8*)&As[(wr + i * 16 + l15) * BK + kh * 32 + q * 8];
#pragma unroll
        for (int j = 0; j < 4; ++j)
          bf[j] = *(const bf16x8*)&Bs[(wc + j * 16 + l15) * BK + kh * 32 + q * 8];
#pragma unroll
        for (int i = 0; i < 4; ++i)
#pragma unroll
          for (int j = 0; j < 4; ++j)
            acc[i][j] = __builtin_amdgcn_mfma_f32_16x16x32_bf16(af[i], bf[j], acc[i][j], 0, 0, 0);
      }
    }

    // Epilogue per 64-col half: bf16 dump -> (chunk max from stored, Sc store).
#pragma unroll
    for (int half = 0; half < 2; ++half) {
      if ((w >> 1) == half) {
#pragma unroll
        for (int i = 0; i < 4; ++i)
#pragma unroll
          for (int j = 0; j < 4; ++j)
#pragma unroll
            for (int rg = 0; rg < 4; ++rg)
              Csb[(wr + i * 16 + q * 4 + rg) * 72 + j * 16 + l15] = f2bf(acc[i][j][rg]);
      }
      __syncthreads();
      float m = -INFINITY;
      uint4 buf[4];
#pragma unroll
      for (int k = 0; k < 4; ++k) {
        buf[k] = *(const uint4*)&Csb[rr * 72 + hq * 32 + k * 8];
        const unsigned int uu[4] = {buf[k].x, buf[k].y, buf[k].z, buf[k].w};
#pragma unroll
        for (int e = 0; e < 4; ++e) {
          m = fmaxf(m, __uint_as_float(uu[e] << 16));
          m = fmaxf(m, __uint_as_float(uu[e] & 0xFFFF0000u));
        }
      }
      tmax[(size_t)(rowBase + rr) * NQ + tileG * 4 + half * 2 + hq] = m;
      uint4* dst = (uint4*)&Sc[(size_t)(rowBase + rr) * NROWS + colBase + half * 64 + hq * 32];
#pragma unroll
      for (int k = 0; k < 4; ++k) dst[k] = buf[k];
      __syncthreads();   // readback done before next dump overwrites Csb
    }
  }
}

// ---------------------------------------------------------------------------
// Collect (+ inlined per-row threshold): wave per row. t = (10th-best of the
// row's 256 group maxes) - TMARGIN via 10-round wave-max knockout; then scan
// stored bf16 logits vs t, append candidates (LDS counter).
// ---------------------------------------------------------------------------
__global__ __launch_bounds__(256)
void collect_scan(const unsigned short* __restrict__ Sc,
                  const float* __restrict__ tmax,
                  int* __restrict__ cnt, int* __restrict__ cand) {
  __shared__ int lcnt[4];
  const int lane = threadIdx.x & 63;
  const int wid = threadIdx.x >> 6;
  const int r = blockIdx.x * 4 + wid;

  if (threadIdx.x < 4) lcnt[threadIdx.x] = 0;
  __syncthreads();

  // --- threshold: 10 rounds of wave-max knockout over 256 group maxes ---
  const f32x4 gm = *(const f32x4*)&tmax[(size_t)r * NQ + lane * 4];
  float a0 = gm[0], a1 = gm[1], a2 = gm[2], a3 = gm[3];
  float g = -INFINITY;
#pragma unroll 1
  for (int j = 0; j < TOPK; ++j) {
    const float lm = fmaxf(fmaxf(a0, a1), fmaxf(a2, a3));
    g = lm;
#pragma unroll
    for (int off = 32; off > 0; off >>= 1) g = fmaxf(g, __shfl_xor(g, off, 64));
    const unsigned long long ball = __ballot(lm == g);
    const int src = __ffsll((long long)ball) - 1;
    if (lane == src) {
      if      (a0 == g) a0 = -INFINITY;
      else if (a1 == g) a1 = -INFINITY;
      else if (a2 == g) a2 = -INFINITY;
      else              a3 = -INFINITY;
    }
  }
  const float tt = g - TMARGIN;

  // --- scan the stored bf16 logit row ---
  const unsigned short* row = Sc + (size_t)r * NROWS;
#pragma unroll 1
  for (int it = 0; it < NROWS / 512; ++it) {
    const int c0 = it * 512 + lane * 8;
    const uint4 u = *(const uint4*)&row[c0];
    const unsigned int uu[4] = {u.x, u.y, u.z, u.w};
#pragma unroll
    for (int e = 0; e < 4; ++e) {
      const float lo = __uint_as_float(uu[e] << 16);
      const float hi = __uint_as_float(uu[e] & 0xFFFF0000u);
      if (lo >= tt) {
        const int p = atomicAdd(&lcnt[wid], 1);
        if (p < CAP) cand[(size_t)r * CAP + p] = c0 + 2 * e;
      }
      if (hi >= tt) {
        const int p = atomicAdd(&lcnt[wid], 1);
        if (p < CAP) cand[(size_t)r * CAP + p] = c0 + 2 * e + 1;
      }
    }
  }
  __syncthreads();
  if (threadIdx.x < 4) cnt[blockIdx.x * 4 + threadIdx.x] = min(lcnt[threadIdx.x], CAP);
}

// ---------------------------------------------------------------------------
// Rescore + finalize fused: wave per row; lane per candidate slot. Chain is
// BIT-IDENTICAL to rounds 3-8 (sequential fmaf k=0..511, then *SCALE).
// Top-10 via deterministic wave-max (tie: min col); softmax summed in the
// same sequential order as the old finalize. Output: [src][dst][weight].
// ---------------------------------------------------------------------------
__global__ __launch_bounds__(256)
void rescore_topk(const float* __restrict__ Eh, const float* __restrict__ Et,
                  const int* __restrict__ cnt, const int* __restrict__ cand,
                  float* __restrict__ out) {
  const int lane = threadIdx.x & 63;
  const int r = blockIdx.x * 4 + (threadIdx.x >> 6);
  const int n = cnt[r];
  const bool active = lane < n;
  const int col = active ? cand[(size_t)r * CAP + lane] : 0;

  const float* a = Eh + (size_t)r * DIMK;
  const float* b = Et + (size_t)col * DIMK;
  float p = 0.f;
#pragma unroll 4
  for (int k = 0; k < DIMK; k += 4) {
    const float4 av = *(const float4*)&a[k];
    const float4 bv = *(const float4*)&b[k];
    p = fmaf(av.x, bv.x, p);
    p = fmaf(av.y, bv.y, p);
    p = fmaf(av.z, bv.z, p);
    p = fmaf(av.w, bv.w, p);
  }
  float v = active ? p * SCALE : -INFINITY;
  const int vc = active ? col : 0x7FFFFFFF;

  // 10 rounds of wave-max (tie -> min col); lane j keeps round-j winner.
  float myv = -INFINITY; int myc = 0; float m = 0.f;
  float vv = v; int cc2 = vc;
#pragma unroll 1
  for (int j = 0; j < TOPK; ++j) {
    float bvv = vv; int bcc = cc2;
#pragma unroll
    for (int off = 32; off > 0; off >>= 1) {
      const float ov = __shfl_xor(bvv, off, 64);
      const int oc = __shfl_xor(bcc, off, 64);
      if (ov > bvv || (ov == bvv && oc < bcc)) { bvv = ov; bcc = oc; }
    }
    if (j == 0) m = bvv;
    if (lane == j) { myv = bvv; myc = bcc; }
    if (vv == bvv && cc2 == bcc) vv = -INFINITY;   // knock out (cols unique)
  }

  // softmax: gather the 10 values, sum sequentially (same order as before).
  float sum = 0.f;
#pragma unroll
  for (int j = 0; j < TOPK; ++j) sum += expf(__shfl(myv, j, 64) - m);
  const float inv = 1.0f / sum;

  if (lane < TOPK) {
    const size_t ro = (size_t)r * TOPK + lane;
    out[ro] = (float)r;                                   // src
    out[(size_t)NROWS * TOPK + ro] = (float)myc;          // dst
    out[2 * (size_t)NROWS * TOPK + ro] = expf(myv - m) * inv;  // weight
  }
}

// ---------------------------------------------------------------------------
extern "C" void kernel_launch(void* const* d_in, const int* in_sizes, int n_in,
                              void* d_out, int out_size, void* d_ws, size_t ws_size,
                              hipStream_t stream) {
  const float* X  = (const float*)d_in[0];
  const float* Wh = (const float*)d_in[1];
  const float* bh = (const float*)d_in[2];
  const float* Wt = (const float*)d_in[3];
  const float* bt = (const float*)d_in[4];
  float* out = (float*)d_out;

  char* ws = (char*)d_ws;
  const size_t embB  = (size_t)NROWS * DIMK * sizeof(float);          // 16 MB
  const size_t embBH = (size_t)NROWS * DIMK * sizeof(unsigned short); //  8 MB
  const size_t tmaxB = (size_t)NROWS * NQ * sizeof(float);            //  8 MB
  const size_t cntB  = (size_t)NROWS * sizeof(int);                   // 32 KB
  const size_t candB = (size_t)NROWS * CAP * sizeof(int);             //  2 MB
  float* Eh   = (float*)ws;
  float* Et   = (float*)(ws + embB);
  unsigned short* Ehb = (unsigned short*)(ws + 2 * embB);
  unsigned short* Etb = (unsigned short*)(ws + 2 * embB + embBH);
  float* tmax = (float*)(ws + 2 * embB + 2 * embBH);
  int*   cnt  = (int*)(ws + 2 * embB + 2 * embBH + tmaxB);
  int*   cand = (int*)(ws + 2 * embB + 2 * embBH + tmaxB + cntB);
  unsigned short* Sc = (unsigned short*)
      (ws + 2 * embB + 2 * embBH + tmaxB + cntB + candB);
  // total ws use ~186 MB (fits: rounds 5-8 used ~186-190 MB)

  dim3 blk(NTHREADS);
  dim3 g1(NROWS / ETM, (2 * DIMK) / ETN);      // 64 x 16
  embed_gemm<<<g1, blk, 0, stream>>>(X, Wh, bh, Wt, bt, Eh, Et, Ehb, Etb);

  dim3 g2(NROWS / BM, NS2);                    // 64 x 16 (strip structure)
  screen_store<<<g2, blk, 0, stream>>>(Ehb, Etb, tmax, Sc);

  collect_scan<<<NROWS / 4, blk, 0, stream>>>(Sc, tmax, cnt, cand);

  rescore_topk<<<NROWS / 4, blk, 0, stream>>>(Eh, Et, cnt, cand, out);
}

// Round 10
// 440.500 us; speedup vs baseline: 1.1471x; 1.1471x over previous
//
#include <hip/hip_runtime.h>
#include <math.h>

// Problem constants (reference: N=8192, DIM=512, TOPK=10, all fp32)
#define NROWS 8192
#define DIMK  512
#define TOPK  10
#define SCALE 0.044194173824159223f   // fp32(512**-0.5)

// Phase-1 embed GEMM tiling (fp32 VALU): 128x64 tile, 8x4 micro-tile.
#define ETM 128
#define ETN 64
#define ETK 32
#define NTHREADS 256

// Screen GEMM tiling (bf16 MFMA) — round-7 structure (measured 157 us)
#define BM 128
#define BN 128
#define BK 32
#define NS2 16                    // column strips
#define SCOLS2 (NROWS / NS2)      // 512 cols per strip (4 tiles)
#define NQ 256                    // 32-col groups per row (8192/32)
#define CAP 64                    // max candidates per row
#define TMARGIN 2.0f              // bf16-gemm noise (~0.65) + bf16-storage (~0.35) << 2.0

typedef __attribute__((ext_vector_type(8))) short bf16x8;   // 8 bf16 = 4 VGPRs
typedef __attribute__((ext_vector_type(4))) float f32x4;

__device__ __forceinline__ unsigned short f2bf(float f) {   // RNE fp32->bf16
  unsigned int u = __float_as_uint(f);
  u = (u + 0x7FFF + ((u >> 16) & 1)) >> 16;
  return (unsigned short)u;
}

// async global->LDS, 16B per lane; lds ptr must be wave-uniform base
__device__ __forceinline__ void gld16(const void* g, const void* lds) {
  __builtin_amdgcn_global_load_lds(
      (const __attribute__((address_space(1))) void*)g,
      (__attribute__((address_space(3))) void*)lds, 16, 0, 0);
}

// ---------------------------------------------------------------------------
// Phase 1: E = X @ W^T + b (fp32 exact) + bf16 copies. 128x64 tile, 8x4
// micro-tile. Per-element k-chain: sequential ascending fmaf + bias at end
// -> BIT-IDENTICAL Eh/Et vs rounds 3-9 (rank near-ties depend on it).
// ---------------------------------------------------------------------------
__global__ __launch_bounds__(NTHREADS, 4)
void embed_gemm(const float* __restrict__ X,
                const float* __restrict__ Wh, const float* __restrict__ bh,
                const float* __restrict__ Wt, const float* __restrict__ bt,
                float* __restrict__ Eh, float* __restrict__ Et,
                unsigned short* __restrict__ Ehb, unsigned short* __restrict__ Etb) {
  __shared__ float As[ETK][ETM + 4];   // d-major, 16.5 KB
  __shared__ float Bs[ETK][ETN + 4];   // 8.5 KB

  const int tid = threadIdx.x;
  const int rowBase = blockIdx.x * ETM;
  const int colBase = blockIdx.y * ETN;          // 0..960 over [Wh|Wt]
  const float* W  = (colBase < DIMK) ? Wh : Wt;
  const float* bb = (colBase < DIMK) ? bh : bt;
  float* Out            = (colBase < DIMK) ? Eh : Et;
  unsigned short* Outb  = (colBase < DIMK) ? Ehb : Etb;
  const int colOff = colBase & (DIMK - 1);

  const int tx = tid & 15, ty = tid >> 4;
  float acc[8][4];
#pragma unroll
  for (int r = 0; r < 8; ++r)
#pragma unroll
    for (int c = 0; c < 4; ++c) acc[r][c] = 0.f;

  for (int kt = 0; kt < DIMK; kt += ETK) {
    __syncthreads();
#pragma unroll
    for (int u = 0; u < 4; ++u) {      // A tile: 1024 float4
      const int idx = tid + u * NTHREADS;
      const int r = idx >> 3;
      const int dc = idx & 7;
      const float4 av = *(const float4*)&X[(size_t)(rowBase + r) * DIMK + kt + dc * 4];
      As[dc * 4 + 0][r] = av.x; As[dc * 4 + 1][r] = av.y;
      As[dc * 4 + 2][r] = av.z; As[dc * 4 + 3][r] = av.w;
    }
#pragma unroll
    for (int u = 0; u < 2; ++u) {      // B tile: 512 float4
      const int idx = tid + u * NTHREADS;
      const int r = idx >> 3;
      const int dc = idx & 7;
      const float4 bv = *(const float4*)&W[(size_t)(colOff + r) * DIMK + kt + dc * 4];
      Bs[dc * 4 + 0][r] = bv.x; Bs[dc * 4 + 1][r] = bv.y;
      Bs[dc * 4 + 2][r] = bv.z; Bs[dc * 4 + 3][r] = bv.w;
    }
    __syncthreads();
#pragma unroll 8
    for (int k = 0; k < ETK; ++k) {
      const float4 a0 = *(const float4*)&As[k][ty * 4];
      const float4 a1 = *(const float4*)&As[k][64 + ty * 4];
      const float4 b  = *(const float4*)&Bs[k][tx * 4];
      const float ar[8] = {a0.x, a0.y, a0.z, a0.w, a1.x, a1.y, a1.z, a1.w};
      const float br[4] = {b.x, b.y, b.z, b.w};
#pragma unroll
      for (int r = 0; r < 8; ++r)
#pragma unroll
        for (int c = 0; c < 4; ++c)
          acc[r][c] = fmaf(ar[r], br[c], acc[r][c]);
    }
  }

  const float4 bv = *(const float4*)&bb[colOff + tx * 4];
  const float br[4] = {bv.x, bv.y, bv.z, bv.w};
#pragma unroll
  for (int r = 0; r < 8; ++r) {
    const int row = rowBase + ((r < 4) ? (ty * 4 + r) : (64 + ty * 4 + r - 4));
    float4 o;
    o.x = acc[r][0] + br[0]; o.y = acc[r][1] + br[1];
    o.z = acc[r][2] + br[2]; o.w = acc[r][3] + br[3];
    const size_t off = (size_t)row * DIMK + colOff + tx * 4;
    *(float4*)&Out[off] = o;
    ushort4 ob;
    ob.x = f2bf(o.x); ob.y = f2bf(o.y); ob.z = f2bf(o.z); ob.w = f2bf(o.w);
    *(ushort4*)&Outb[off] = ob;
  }
}

// ---------------------------------------------------------------------------
// Screen (round-7 code, measured 157 us) + ONE change: XCD-locality swizzle.
// 1-D grid of 1024; xcd = b&7 (dispatch round-robin), c = b>>3. Mapping
// strip = c>>3, rowBlk = ((c&7)<<3)|xcd clusters co-resident blocks per XCD
// onto ~2 strips + ~12 row-slabs -> ~2.5 MB working set fits the 4 MB L2.
// Pure index remap; per-block work identical -> numerics unchanged.
// ---------------------------------------------------------------------------
__global__ __launch_bounds__(256, 3)
void screen_store(const unsigned short* __restrict__ Ehb,
                  const unsigned short* __restrict__ Etb,
                  float* __restrict__ tmax, unsigned short* __restrict__ Sc) {
  __shared__ unsigned short As[BM * BK];   // 8 KB
  __shared__ unsigned short Bs[BN * BK];   // 8 KB
  __shared__ float Cs[BM][68];             // 34.8 KB; rows 16B-aligned

  const int b = blockIdx.x;
  const int xcd = b & 7, c = b >> 3;
  const int strip = c >> 3;
  const int rowBlk = ((c & 7) << 3) | xcd;

  const int tid = threadIdx.x;
  const int rowBase = rowBlk * BM;
  const int w = tid >> 6, lane = tid & 63;
  const int q = lane >> 4, l15 = lane & 15;
  const int wr = (w & 1) * 64, wc = (w >> 1) * 64;
  const int rr = tid >> 1, hq = tid & 1;   // epilogue: row / 32-col chunk

  const int c0 = tid, c1 = tid + 256;
  const int wb0 = __builtin_amdgcn_readfirstlane(tid & ~63);
  const int wb1 = wb0 + 256;
  const int ar0 = c0 >> 2, ac0 = (c0 & 3) * 8;
  const int ar1 = c1 >> 2, ac1 = (c1 & 3) * 8;

  for (int ct = 0; ct < SCOLS2; ct += BN) {
    const int colBase = strip * SCOLS2 + ct;
    const int tileG = colBase >> 7;          // global 128-col tile index
    f32x4 acc[4][4];
#pragma unroll
    for (int i = 0; i < 4; ++i)
#pragma unroll
      for (int j = 0; j < 4; ++j) acc[i][j] = (f32x4){0.f, 0.f, 0.f, 0.f};

    for (int kt = 0; kt < DIMK; kt += BK) {
      __syncthreads();
      gld16(Ehb + (size_t)(rowBase + ar0) * DIMK + kt + ac0, As + wb0 * 8);
      gld16(Ehb + (size_t)(rowBase + ar1) * DIMK + kt + ac1, As + wb1 * 8);
      gld16(Etb + (size_t)(colBase + ar0) * DIMK + kt + ac0, Bs + wb0 * 8);
      gld16(Etb + (size_t)(colBase + ar1) * DIMK + kt + ac1, Bs + wb1 * 8);
      __syncthreads();   // drains vmcnt (global_load_lds) + orders LDS

      bf16x8 af[4], bf[4];
#pragma unroll
      for (int i = 0; i < 4; ++i)
        af[i] = *(const bf16x8*)&As[(wr + i * 16 + l15) * BK + q * 8];
#pragma unroll
      for (int j = 0; j < 4; ++j)
        bf[j] = *(const bf16x8*)&Bs[(wc + j * 16 + l15) * BK + q * 8];
#pragma unroll
      for (int i = 0; i < 4; ++i)
#pragma unroll
        for (int j = 0; j < 4; ++j)
          acc[i][j] = __builtin_amdgcn_mfma_f32_16x16x32_bf16(af[i], bf[j], acc[i][j], 0, 0, 0);
    }

    // Epilogue per 64-col half: dump -> (chunk max, bf16 store).
#pragma unroll
    for (int half = 0; half < 2; ++half) {
      if ((w >> 1) == half) {
#pragma unroll
        for (int i = 0; i < 4; ++i)
#pragma unroll
          for (int j = 0; j < 4; ++j)
#pragma unroll
            for (int rg = 0; rg < 4; ++rg)
              Cs[wr + i * 16 + q * 4 + rg][j * 16 + l15] = acc[i][j][rg];
      }
      __syncthreads();
      float m = -INFINITY;
      unsigned int pk[16];
#pragma unroll
      for (int k = 0; k < 8; ++k) {
        const f32x4 v = *(const f32x4*)&Cs[rr][hq * 32 + k * 4];
        m = fmaxf(m, fmaxf(fmaxf(v[0], v[1]), fmaxf(v[2], v[3])));
        pk[2 * k]     = (unsigned int)f2bf(v[0]) | ((unsigned int)f2bf(v[1]) << 16);
        pk[2 * k + 1] = (unsigned int)f2bf(v[2]) | ((unsigned int)f2bf(v[3]) << 16);
      }
      tmax[(size_t)(rowBase + rr) * NQ + tileG * 4 + half * 2 + hq] = m;
      unsigned int* dst = (unsigned int*)
          &Sc[(size_t)(rowBase + rr) * NROWS + colBase + half * 64 + hq * 32];
#pragma unroll
      for (int k = 0; k < 4; ++k)
        *(uint4*)&dst[k * 4] = make_uint4(pk[4*k], pk[4*k+1], pk[4*k+2], pk[4*k+3]);
      __syncthreads();   // readback done before next dump overwrites Cs
    }
  }
}

// ---------------------------------------------------------------------------
// Collect (+ inlined per-row threshold): wave per row. t = (10th-best of the
// row's 256 group maxes) - TMARGIN via 10-round wave-max knockout; then scan
// stored bf16 logits vs t, append candidates (LDS counter).
// ---------------------------------------------------------------------------
__global__ __launch_bounds__(256)
void collect_scan(const unsigned short* __restrict__ Sc,
                  const float* __restrict__ tmax,
                  int* __restrict__ cnt, int* __restrict__ cand) {
  __shared__ int lcnt[4];
  const int lane = threadIdx.x & 63;
  const int wid = threadIdx.x >> 6;
  const int r = blockIdx.x * 4 + wid;

  if (threadIdx.x < 4) lcnt[threadIdx.x] = 0;
  __syncthreads();

  // --- threshold: 10 rounds of wave-max knockout over 256 group maxes ---
  const f32x4 gm = *(const f32x4*)&tmax[(size_t)r * NQ + lane * 4];
  float a0 = gm[0], a1 = gm[1], a2 = gm[2], a3 = gm[3];
  float g = -INFINITY;
#pragma unroll 1
  for (int j = 0; j < TOPK; ++j) {
    const float lm = fmaxf(fmaxf(a0, a1), fmaxf(a2, a3));
    g = lm;
#pragma unroll
    for (int off = 32; off > 0; off >>= 1) g = fmaxf(g, __shfl_xor(g, off, 64));
    const unsigned long long ball = __ballot(lm == g);
    const int src = __ffsll((long long)ball) - 1;
    if (lane == src) {
      if      (a0 == g) a0 = -INFINITY;
      else if (a1 == g) a1 = -INFINITY;
      else if (a2 == g) a2 = -INFINITY;
      else              a3 = -INFINITY;
    }
  }
  const float tt = g - TMARGIN;

  // --- scan the stored bf16 logit row ---
  const unsigned short* row = Sc + (size_t)r * NROWS;
#pragma unroll 1
  for (int it = 0; it < NROWS / 512; ++it) {
    const int c0 = it * 512 + lane * 8;
    const uint4 u = *(const uint4*)&row[c0];
    const unsigned int uu[4] = {u.x, u.y, u.z, u.w};
#pragma unroll
    for (int e = 0; e < 4; ++e) {
      const float lo = __uint_as_float(uu[e] << 16);
      const float hi = __uint_as_float(uu[e] & 0xFFFF0000u);
      if (lo >= tt) {
        const int p = atomicAdd(&lcnt[wid], 1);
        if (p < CAP) cand[(size_t)r * CAP + p] = c0 + 2 * e;
      }
      if (hi >= tt) {
        const int p = atomicAdd(&lcnt[wid], 1);
        if (p < CAP) cand[(size_t)r * CAP + p] = c0 + 2 * e + 1;
      }
    }
  }
  __syncthreads();
  if (threadIdx.x < 4) cnt[blockIdx.x * 4 + threadIdx.x] = min(lcnt[threadIdx.x], CAP);
}

// ---------------------------------------------------------------------------
// Rescore + finalize fused: wave per row; lane per candidate slot. Chain is
// BIT-IDENTICAL to rounds 3-9 (sequential fmaf k=0..511, then *SCALE).
// Top-10 via deterministic wave-max (tie: min col); softmax summed in the
// same sequential order. Output: [src][dst][weight].
// ---------------------------------------------------------------------------
__global__ __launch_bounds__(256)
void rescore_topk(const float* __restrict__ Eh, const float* __restrict__ Et,
                  const int* __restrict__ cnt, const int* __restrict__ cand,
                  float* __restrict__ out) {
  const int lane = threadIdx.x & 63;
  const int r = blockIdx.x * 4 + (threadIdx.x >> 6);
  const int n = cnt[r];
  const bool active = lane < n;
  const int col = active ? cand[(size_t)r * CAP + lane] : 0;

  const float* a = Eh + (size_t)r * DIMK;
  const float* b = Et + (size_t)col * DIMK;
  float p = 0.f;
#pragma unroll 4
  for (int k = 0; k < DIMK; k += 4) {
    const float4 av = *(const float4*)&a[k];
    const float4 bv = *(const float4*)&b[k];
    p = fmaf(av.x, bv.x, p);
    p = fmaf(av.y, bv.y, p);
    p = fmaf(av.z, bv.z, p);
    p = fmaf(av.w, bv.w, p);
  }
  float v = active ? p * SCALE : -INFINITY;
  const int vc = active ? col : 0x7FFFFFFF;

  // 10 rounds of wave-max (tie -> min col); lane j keeps round-j winner.
  float myv = -INFINITY; int myc = 0; float m = 0.f;
  float vv = v; int cc2 = vc;
#pragma unroll 1
  for (int j = 0; j < TOPK; ++j) {
    float bvv = vv; int bcc = cc2;
#pragma unroll
    for (int off = 32; off > 0; off >>= 1) {
      const float ov = __shfl_xor(bvv, off, 64);
      const int oc = __shfl_xor(bcc, off, 64);
      if (ov > bvv || (ov == bvv && oc < bcc)) { bvv = ov; bcc = oc; }
    }
    if (j == 0) m = bvv;
    if (lane == j) { myv = bvv; myc = bcc; }
    if (vv == bvv && cc2 == bcc) vv = -INFINITY;   // knock out (cols unique)
  }

  // softmax: gather the 10 values, sum sequentially (same order as before).
  float sum = 0.f;
#pragma unroll
  for (int j = 0; j < TOPK; ++j) sum += expf(__shfl(myv, j, 64) - m);
  const float inv = 1.0f / sum;

  if (lane < TOPK) {
    const size_t ro = (size_t)r * TOPK + lane;
    out[ro] = (float)r;                                   // src
    out[(size_t)NROWS * TOPK + ro] = (float)myc;          // dst
    out[2 * (size_t)NROWS * TOPK + ro] = expf(myv - m) * inv;  // weight
  }
}

// ---------------------------------------------------------------------------
extern "C" void kernel_launch(void* const* d_in, const int* in_sizes, int n_in,
                              void* d_out, int out_size, void* d_ws, size_t ws_size,
                              hipStream_t stream) {
  const float* X  = (const float*)d_in[0];
  const float* Wh = (const float*)d_in[1];
  const float* bh = (const float*)d_in[2];
  const float* Wt = (const float*)d_in[3];
  const float* bt = (const float*)d_in[4];
  float* out = (float*)d_out;

  char* ws = (char*)d_ws;
  const size_t embB  = (size_t)NROWS * DIMK * sizeof(float);          // 16 MB
  const size_t embBH = (size_t)NROWS * DIMK * sizeof(unsigned short); //  8 MB
  const size_t tmaxB = (size_t)NROWS * NQ * sizeof(float);            //  8 MB
  const size_t cntB  = (size_t)NROWS * sizeof(int);                   // 32 KB
  const size_t candB = (size_t)NROWS * CAP * sizeof(int);             //  2 MB
  float* Eh   = (float*)ws;
  float* Et   = (float*)(ws + embB);
  unsigned short* Ehb = (unsigned short*)(ws + 2 * embB);
  unsigned short* Etb = (unsigned short*)(ws + 2 * embB + embBH);
  float* tmax = (float*)(ws + 2 * embB + 2 * embBH);
  int*   cnt  = (int*)(ws + 2 * embB + 2 * embBH + tmaxB);
  int*   cand = (int*)(ws + 2 * embB + 2 * embBH + tmaxB + cntB);
  unsigned short* Sc = (unsigned short*)
      (ws + 2 * embB + 2 * embBH + tmaxB + cntB + candB);
  // total ws use ~186 MB

  dim3 blk(NTHREADS);
  dim3 g1(NROWS / ETM, (2 * DIMK) / ETN);      // 64 x 16
  embed_gemm<<<g1, blk, 0, stream>>>(X, Wh, bh, Wt, bt, Eh, Et, Ehb, Etb);

  screen_store<<<(NROWS / BM) * NS2, blk, 0, stream>>>(Ehb, Etb, tmax, Sc);

  collect_scan<<<NROWS / 4, blk, 0, stream>>>(Sc, tmax, cnt, cand);

  rescore_topk<<<NROWS / 4, blk, 0, stream>>>(Eh, Et, cnt, cand, out);
}

// Round 11
// 429.408 us; speedup vs baseline: 1.1768x; 1.0258x over previous
//
#include <hip/hip_runtime.h>
#include <math.h>

// Problem constants (reference: N=8192, DIM=512, TOPK=10, all fp32)
#define NROWS 8192
#define DIMK  512
#define TOPK  10
#define SCALE 0.044194173824159223f   // fp32(512**-0.5)

// Phase-1 embed GEMM tiling (fp32 VALU): 128x64 tile, 8x4 micro-tile.
#define ETM 128
#define ETN 64
#define ETK 32
#define NTHREADS 256

// Screen GEMM tiling (bf16 MFMA) — round-7 strip structure + dbuf staging
#define BM 128
#define BN 128
#define BK 32
#define NS2 16                    // column strips
#define SCOLS2 (NROWS / NS2)      // 512 cols per strip (4 tiles)
#define NQ 256                    // 32-col groups per row (8192/32)
#define CAP 64                    // max candidates per row
#define TMARGIN 2.0f              // bf16-gemm noise (~0.65) + bf16-storage (~0.35) << 2.0

typedef __attribute__((ext_vector_type(8))) short bf16x8;   // 8 bf16 = 4 VGPRs
typedef __attribute__((ext_vector_type(4))) float f32x4;

__device__ __forceinline__ unsigned short f2bf(float f) {   // RNE fp32->bf16
  unsigned int u = __float_as_uint(f);
  u = (u + 0x7FFF + ((u >> 16) & 1)) >> 16;
  return (unsigned short)u;
}

// async global->LDS, 16B per lane; lds ptr must be wave-uniform base
__device__ __forceinline__ void gld16(const void* g, const void* lds) {
  __builtin_amdgcn_global_load_lds(
      (const __attribute__((address_space(1))) void*)g,
      (__attribute__((address_space(3))) void*)lds, 16, 0, 0);
}

// ---------------------------------------------------------------------------
// Phase 1: E = X @ W^T + b (fp32 exact) + bf16 copies. 128x64 tile, 8x4
// micro-tile. Per-element k-chain: sequential ascending fmaf + bias at end
// -> BIT-IDENTICAL Eh/Et vs rounds 3-10 (rank near-ties depend on it).
// ---------------------------------------------------------------------------
__global__ __launch_bounds__(NTHREADS, 4)
void embed_gemm(const float* __restrict__ X,
                const float* __restrict__ Wh, const float* __restrict__ bh,
                const float* __restrict__ Wt, const float* __restrict__ bt,
                float* __restrict__ Eh, float* __restrict__ Et,
                unsigned short* __restrict__ Ehb, unsigned short* __restrict__ Etb) {
  __shared__ float As[ETK][ETM + 4];   // d-major, 16.5 KB
  __shared__ float Bs[ETK][ETN + 4];   // 8.5 KB

  const int tid = threadIdx.x;
  const int rowBase = blockIdx.x * ETM;
  const int colBase = blockIdx.y * ETN;          // 0..960 over [Wh|Wt]
  const float* W  = (colBase < DIMK) ? Wh : Wt;
  const float* bb = (colBase < DIMK) ? bh : bt;
  float* Out            = (colBase < DIMK) ? Eh : Et;
  unsigned short* Outb  = (colBase < DIMK) ? Ehb : Etb;
  const int colOff = colBase & (DIMK - 1);

  const int tx = tid & 15, ty = tid >> 4;
  float acc[8][4];
#pragma unroll
  for (int r = 0; r < 8; ++r)
#pragma unroll
    for (int c = 0; c < 4; ++c) acc[r][c] = 0.f;

  for (int kt = 0; kt < DIMK; kt += ETK) {
    __syncthreads();
#pragma unroll
    for (int u = 0; u < 4; ++u) {      // A tile: 1024 float4
      const int idx = tid + u * NTHREADS;
      const int r = idx >> 3;
      const int dc = idx & 7;
      const float4 av = *(const float4*)&X[(size_t)(rowBase + r) * DIMK + kt + dc * 4];
      As[dc * 4 + 0][r] = av.x; As[dc * 4 + 1][r] = av.y;
      As[dc * 4 + 2][r] = av.z; As[dc * 4 + 3][r] = av.w;
    }
#pragma unroll
    for (int u = 0; u < 2; ++u) {      // B tile: 512 float4
      const int idx = tid + u * NTHREADS;
      const int r = idx >> 3;
      const int dc = idx & 7;
      const float4 bv = *(const float4*)&W[(size_t)(colOff + r) * DIMK + kt + dc * 4];
      Bs[dc * 4 + 0][r] = bv.x; Bs[dc * 4 + 1][r] = bv.y;
      Bs[dc * 4 + 2][r] = bv.z; Bs[dc * 4 + 3][r] = bv.w;
    }
    __syncthreads();
#pragma unroll 8
    for (int k = 0; k < ETK; ++k) {
      const float4 a0 = *(const float4*)&As[k][ty * 4];
      const float4 a1 = *(const float4*)&As[k][64 + ty * 4];
      const float4 b  = *(const float4*)&Bs[k][tx * 4];
      const float ar[8] = {a0.x, a0.y, a0.z, a0.w, a1.x, a1.y, a1.z, a1.w};
      const float br[4] = {b.x, b.y, b.z, b.w};
#pragma unroll
      for (int r = 0; r < 8; ++r)
#pragma unroll
        for (int c = 0; c < 4; ++c)
          acc[r][c] = fmaf(ar[r], br[c], acc[r][c]);
    }
  }

  const float4 bv = *(const float4*)&bb[colOff + tx * 4];
  const float br[4] = {bv.x, bv.y, bv.z, bv.w};
#pragma unroll
  for (int r = 0; r < 8; ++r) {
    const int row = rowBase + ((r < 4) ? (ty * 4 + r) : (64 + ty * 4 + r - 4));
    float4 o;
    o.x = acc[r][0] + br[0]; o.y = acc[r][1] + br[1];
    o.z = acc[r][2] + br[2]; o.w = acc[r][3] + br[3];
    const size_t off = (size_t)row * DIMK + colOff + tx * 4;
    *(float4*)&Out[off] = o;
    ushort4 ob;
    ob.x = f2bf(o.x); ob.y = f2bf(o.y); ob.z = f2bf(o.z); ob.w = f2bf(o.w);
    *(ushort4*)&Outb[off] = ob;
  }
}

// ---------------------------------------------------------------------------
// Screen: round-7 strip structure (2-D grid, measured FETCH 84MB) with
// double-buffered As/Bs staging (1 barrier/kt instead of 2; loads for kt+1
// issued BEFORE computing kt so the barrier's vmcnt drain is overlapped) and
// bf16 Csb epilogue (round-8, proven). LDS = 2*8 + 2*8 + 18 = 50 KB ->
// 3 blocks/CU (pinned: 4 blocks/CU thrashed L2 in round 8). MFMA sequence is
// the same 16 ascending k-chunks -> acc BIT-IDENTICAL to rounds 7-10.
// ---------------------------------------------------------------------------
__global__ __launch_bounds__(256, 3)
void screen_store(const unsigned short* __restrict__ Ehb,
                  const unsigned short* __restrict__ Etb,
                  float* __restrict__ tmax, unsigned short* __restrict__ Sc) {
  __shared__ unsigned short As[2][BM * BK];   // 2 x 8 KB
  __shared__ unsigned short Bs[2][BN * BK];   // 2 x 8 KB
  __shared__ unsigned short Csb[BM * 72];     // 18 KB, stride 72

  const int tid = threadIdx.x;
  const int rowBase = blockIdx.x * BM;
  const int strip = blockIdx.y;
  const int w = tid >> 6, lane = tid & 63;
  const int q = lane >> 4, l15 = lane & 15;
  const int wr = (w & 1) * 64, wc = (w >> 1) * 64;
  const int rr = tid >> 1, hq = tid & 1;   // epilogue: row / 32-col chunk

  const int c0 = tid, c1 = tid + 256;
  const int wb0 = __builtin_amdgcn_readfirstlane(tid & ~63);
  const int wb1 = wb0 + 256;
  const int ar0 = c0 >> 2, ac0 = (c0 & 3) * 8;
  const int ar1 = c1 >> 2, ac1 = (c1 & 3) * 8;

  for (int ct = 0; ct < SCOLS2; ct += BN) {
    const int colBase = strip * SCOLS2 + ct;
    const int tileG = colBase >> 7;          // global 128-col tile index
    f32x4 acc[4][4];
#pragma unroll
    for (int i = 0; i < 4; ++i)
#pragma unroll
      for (int j = 0; j < 4; ++j) acc[i][j] = (f32x4){0.f, 0.f, 0.f, 0.f};

    auto stage = [&](int buf, int kt) {
      gld16(Ehb + (size_t)(rowBase + ar0) * DIMK + kt + ac0, As[buf] + wb0 * 8);
      gld16(Ehb + (size_t)(rowBase + ar1) * DIMK + kt + ac1, As[buf] + wb1 * 8);
      gld16(Etb + (size_t)(colBase + ar0) * DIMK + kt + ac0, Bs[buf] + wb0 * 8);
      gld16(Etb + (size_t)(colBase + ar1) * DIMK + kt + ac1, Bs[buf] + wb1 * 8);
    };
    auto compute = [&](int buf) {
      bf16x8 af[4], bf[4];
#pragma unroll
      for (int i = 0; i < 4; ++i)
        af[i] = *(const bf16x8*)&As[buf][(wr + i * 16 + l15) * BK + q * 8];
#pragma unroll
      for (int j = 0; j < 4; ++j)
        bf[j] = *(const bf16x8*)&Bs[buf][(wc + j * 16 + l15) * BK + q * 8];
#pragma unroll
      for (int i = 0; i < 4; ++i)
#pragma unroll
        for (int j = 0; j < 4; ++j)
          acc[i][j] = __builtin_amdgcn_mfma_f32_16x16x32_bf16(af[i], bf[j], acc[i][j], 0, 0, 0);
    };

    // prologue: stage k-chunk 0 into buf 0 (prev epilogue barrier covers WAR)
    stage(0, 0);
    __syncthreads();
    // steady state: 2 k-chunks per step, static buffer indices
#pragma unroll 1
    for (int ki = 0; ki < DIMK / BK; ki += 2) {
      if (ki + 1 < DIMK / BK) stage(1, (ki + 1) * BK);
      compute(0);                  // k-chunk ki (ascending -> acc bit-identical)
      __syncthreads();             // drains stage(1); WAR for next stage(0)
      if (ki + 2 < DIMK / BK) stage(0, (ki + 2) * BK);
      compute(1);                  // k-chunk ki+1
      __syncthreads();
    }

    // Epilogue per 64-col half: bf16 dump -> (chunk max from stored, Sc store).
#pragma unroll
    for (int half = 0; half < 2; ++half) {
      if ((w >> 1) == half) {
#pragma unroll
        for (int i = 0; i < 4; ++i)
#pragma unroll
          for (int j = 0; j < 4; ++j)
#pragma unroll
            for (int rg = 0; rg < 4; ++rg)
              Csb[(wr + i * 16 + q * 4 + rg) * 72 + j * 16 + l15] = f2bf(acc[i][j][rg]);
      }
      __syncthreads();
      float m = -INFINITY;
      uint4 buf4[4];
#pragma unroll
      for (int k = 0; k < 4; ++k) {
        buf4[k] = *(const uint4*)&Csb[rr * 72 + hq * 32 + k * 8];
        const unsigned int uu[4] = {buf4[k].x, buf4[k].y, buf4[k].z, buf4[k].w};
#pragma unroll
        for (int e = 0; e < 4; ++e) {
          m = fmaxf(m, __uint_as_float(uu[e] << 16));
          m = fmaxf(m, __uint_as_float(uu[e] & 0xFFFF0000u));
        }
      }
      tmax[(size_t)(rowBase + rr) * NQ + tileG * 4 + half * 2 + hq] = m;
      uint4* dst = (uint4*)&Sc[(size_t)(rowBase + rr) * NROWS + colBase + half * 64 + hq * 32];
#pragma unroll
      for (int k = 0; k < 4; ++k) dst[k] = buf4[k];
      __syncthreads();   // readback done before next dump overwrites Csb
    }
  }
}

// ---------------------------------------------------------------------------
// Collect (+ inlined per-row threshold): wave per row. t = (10th-best of the
// row's 256 group maxes) - TMARGIN via 10-round wave-max knockout; then scan
// stored bf16 logits vs t, append candidates (LDS counter).
// ---------------------------------------------------------------------------
__global__ __launch_bounds__(256)
void collect_scan(const unsigned short* __restrict__ Sc,
                  const float* __restrict__ tmax,
                  int* __restrict__ cnt, int* __restrict__ cand) {
  __shared__ int lcnt[4];
  const int lane = threadIdx.x & 63;
  const int wid = threadIdx.x >> 6;
  const int r = blockIdx.x * 4 + wid;

  if (threadIdx.x < 4) lcnt[threadIdx.x] = 0;
  __syncthreads();

  // --- threshold: 10 rounds of wave-max knockout over 256 group maxes ---
  const f32x4 gm = *(const f32x4*)&tmax[(size_t)r * NQ + lane * 4];
  float a0 = gm[0], a1 = gm[1], a2 = gm[2], a3 = gm[3];
  float g = -INFINITY;
#pragma unroll 1
  for (int j = 0; j < TOPK; ++j) {
    const float lm = fmaxf(fmaxf(a0, a1), fmaxf(a2, a3));
    g = lm;
#pragma unroll
    for (int off = 32; off > 0; off >>= 1) g = fmaxf(g, __shfl_xor(g, off, 64));
    const unsigned long long ball = __ballot(lm == g);
    const int src = __ffsll((long long)ball) - 1;
    if (lane == src) {
      if      (a0 == g) a0 = -INFINITY;
      else if (a1 == g) a1 = -INFINITY;
      else if (a2 == g) a2 = -INFINITY;
      else              a3 = -INFINITY;
    }
  }
  const float tt = g - TMARGIN;

  // --- scan the stored bf16 logit row ---
  const unsigned short* row = Sc + (size_t)r * NROWS;
#pragma unroll 1
  for (int it = 0; it < NROWS / 512; ++it) {
    const int c0 = it * 512 + lane * 8;
    const uint4 u = *(const uint4*)&row[c0];
    const unsigned int uu[4] = {u.x, u.y, u.z, u.w};
#pragma unroll
    for (int e = 0; e < 4; ++e) {
      const float lo = __uint_as_float(uu[e] << 16);
      const float hi = __uint_as_float(uu[e] & 0xFFFF0000u);
      if (lo >= tt) {
        const int p = atomicAdd(&lcnt[wid], 1);
        if (p < CAP) cand[(size_t)r * CAP + p] = c0 + 2 * e;
      }
      if (hi >= tt) {
        const int p = atomicAdd(&lcnt[wid], 1);
        if (p < CAP) cand[(size_t)r * CAP + p] = c0 + 2 * e + 1;
      }
    }
  }
  __syncthreads();
  if (threadIdx.x < 4) cnt[blockIdx.x * 4 + threadIdx.x] = min(lcnt[threadIdx.x], CAP);
}

// ---------------------------------------------------------------------------
// Rescore + finalize fused: wave per row; lane per candidate slot. Chain is
// BIT-IDENTICAL to rounds 3-10 (sequential fmaf k=0..511, then *SCALE).
// Top-10 via deterministic wave-max (tie: min col); softmax summed in the
// same sequential order. Output: [src][dst][weight].
// ---------------------------------------------------------------------------
__global__ __launch_bounds__(256)
void rescore_topk(const float* __restrict__ Eh, const float* __restrict__ Et,
                  const int* __restrict__ cnt, const int* __restrict__ cand,
                  float* __restrict__ out) {
  const int lane = threadIdx.x & 63;
  const int r = blockIdx.x * 4 + (threadIdx.x >> 6);
  const int n = cnt[r];
  const bool active = lane < n;
  const int col = active ? cand[(size_t)r * CAP + lane] : 0;

  const float* a = Eh + (size_t)r * DIMK;
  const float* b = Et + (size_t)col * DIMK;
  float p = 0.f;
#pragma unroll 4
  for (int k = 0; k < DIMK; k += 4) {
    const float4 av = *(const float4*)&a[k];
    const float4 bv = *(const float4*)&b[k];
    p = fmaf(av.x, bv.x, p);
    p = fmaf(av.y, bv.y, p);
    p = fmaf(av.z, bv.z, p);
    p = fmaf(av.w, bv.w, p);
  }
  float v = active ? p * SCALE : -INFINITY;
  const int vc = active ? col : 0x7FFFFFFF;

  // 10 rounds of wave-max (tie -> min col); lane j keeps round-j winner.
  float myv = -INFINITY; int myc = 0; float m = 0.f;
  float vv = v; int cc2 = vc;
#pragma unroll 1
  for (int j = 0; j < TOPK; ++j) {
    float bvv = vv; int bcc = cc2;
#pragma unroll
    for (int off = 32; off > 0; off >>= 1) {
      const float ov = __shfl_xor(bvv, off, 64);
      const int oc = __shfl_xor(bcc, off, 64);
      if (ov > bvv || (ov == bvv && oc < bcc)) { bvv = ov; bcc = oc; }
    }
    if (j == 0) m = bvv;
    if (lane == j) { myv = bvv; myc = bcc; }
    if (vv == bvv && cc2 == bcc) vv = -INFINITY;   // knock out (cols unique)
  }

  // softmax: gather the 10 values, sum sequentially (same order as before).
  float sum = 0.f;
#pragma unroll
  for (int j = 0; j < TOPK; ++j) sum += expf(__shfl(myv, j, 64) - m);
  const float inv = 1.0f / sum;

  if (lane < TOPK) {
    const size_t ro = (size_t)r * TOPK + lane;
    out[ro] = (float)r;                                   // src
    out[(size_t)NROWS * TOPK + ro] = (float)myc;          // dst
    out[2 * (size_t)NROWS * TOPK + ro] = expf(myv - m) * inv;  // weight
  }
}

// ---------------------------------------------------------------------------
extern "C" void kernel_launch(void* const* d_in, const int* in_sizes, int n_in,
                              void* d_out, int out_size, void* d_ws, size_t ws_size,
                              hipStream_t stream) {
  const float* X  = (const float*)d_in[0];
  const float* Wh = (const float*)d_in[1];
  const float* bh = (const float*)d_in[2];
  const float* Wt = (const float*)d_in[3];
  const float* bt = (const float*)d_in[4];
  float* out = (float*)d_out;

  char* ws = (char*)d_ws;
  const size_t embB  = (size_t)NROWS * DIMK * sizeof(float);          // 16 MB
  const size_t embBH = (size_t)NROWS * DIMK * sizeof(unsigned short); //  8 MB
  const size_t tmaxB = (size_t)NROWS * NQ * sizeof(float);            //  8 MB
  const size_t cntB  = (size_t)NROWS * sizeof(int);                   // 32 KB
  const size_t candB = (size_t)NROWS * CAP * sizeof(int);             //  2 MB
  float* Eh   = (float*)ws;
  float* Et   = (float*)(ws + embB);
  unsigned short* Ehb = (unsigned short*)(ws + 2 * embB);
  unsigned short* Etb = (unsigned short*)(ws + 2 * embB + embBH);
  float* tmax = (float*)(ws + 2 * embB + 2 * embBH);
  int*   cnt  = (int*)(ws + 2 * embB + 2 * embBH + tmaxB);
  int*   cand = (int*)(ws + 2 * embB + 2 * embBH + tmaxB + cntB);
  unsigned short* Sc = (unsigned short*)
      (ws + 2 * embB + 2 * embBH + tmaxB + cntB + candB);
  // total ws use ~186 MB

  dim3 blk(NTHREADS);
  dim3 g1(NROWS / ETM, (2 * DIMK) / ETN);      // 64 x 16
  embed_gemm<<<g1, blk, 0, stream>>>(X, Wh, bh, Wt, bt, Eh, Et, Ehb, Etb);

  dim3 g2(NROWS / BM, NS2);                    // 64 x 16 (round-7 2-D grid)
  screen_store<<<g2, blk, 0, stream>>>(Ehb, Etb, tmax, Sc);

  collect_scan<<<NROWS / 4, blk, 0, stream>>>(Sc, tmax, cnt, cand);

  rescore_topk<<<NROWS / 4, blk, 0, stream>>>(Eh, Et, cnt, cand, out);
}

// Round 12
// 417.546 us; speedup vs baseline: 1.2102x; 1.0284x over previous
//
#include <hip/hip_runtime.h>
#include <math.h>

// Problem constants (reference: N=8192, DIM=512, TOPK=10, all fp32)
#define NROWS 8192
#define DIMK  512
#define TOPK  10
#define SCALE 0.044194173824159223f   // fp32(512**-0.5)

// Phase-1 embed GEMM tiling (fp32 VALU): 128x64 tile, 8x4 micro-tile, dbuf.
#define ETM 128
#define ETN 64
#define ETK 32
#define NTHREADS 256

// Screen GEMM tiling (bf16 MFMA) — round-11 dbuf strip structure (147 us)
#define BM 128
#define BN 128
#define BK 32
#define NS2 16                    // column strips
#define SCOLS2 (NROWS / NS2)      // 512 cols per strip (4 tiles)
#define NQ 256                    // 32-col groups per row (8192/32)
#define CAP 64                    // max candidates per row
#define TMARGIN 2.0f              // bf16-gemm noise (~0.65) + bf16-storage (~0.35) << 2.0

typedef __attribute__((ext_vector_type(8))) short bf16x8;   // 8 bf16 = 4 VGPRs
typedef __attribute__((ext_vector_type(4))) float f32x4;

__device__ __forceinline__ unsigned short f2bf(float f) {   // RNE fp32->bf16
  unsigned int u = __float_as_uint(f);
  u = (u + 0x7FFF + ((u >> 16) & 1)) >> 16;
  return (unsigned short)u;
}

// async global->LDS, 16B per lane; lds ptr must be wave-uniform base
__device__ __forceinline__ void gld16(const void* g, const void* lds) {
  __builtin_amdgcn_global_load_lds(
      (const __attribute__((address_space(1))) void*)g,
      (__attribute__((address_space(3))) void*)lds, 16, 0, 0);
}

// ---------------------------------------------------------------------------
// Phase 1: E = X @ W^T + b (fp32 exact) + bf16 copies. 128x64 tile, 8x4
// micro-tile. NEW (r12): double-buffered LDS staging (1 barrier/kt, loads
// overlap compute) + unroll 4 (live set ~95 VGPR, no spill) + (256,3)
// (VGPR cap ~168, LDS 51.2 KB -> 3 blocks/CU). Per-element k-chain is the
// same sequential ascending fmaf + bias at end -> BIT-IDENTICAL Eh/Et vs
// rounds 3-11 (rank near-ties depend on it).
// ---------------------------------------------------------------------------
__global__ __launch_bounds__(NTHREADS, 3)
void embed_gemm(const float* __restrict__ X,
                const float* __restrict__ Wh, const float* __restrict__ bh,
                const float* __restrict__ Wt, const float* __restrict__ bt,
                float* __restrict__ Eh, float* __restrict__ Et,
                unsigned short* __restrict__ Ehb, unsigned short* __restrict__ Etb) {
  __shared__ float As[2][ETK][ETM + 4];   // 2 x 16.5 KB, d-major
  __shared__ float Bs[2][ETK][ETN + 4];   // 2 x 8.5 KB

  const int tid = threadIdx.x;
  const int rowBase = blockIdx.x * ETM;
  const int colBase = blockIdx.y * ETN;          // 0..960 over [Wh|Wt]
  const float* W  = (colBase < DIMK) ? Wh : Wt;
  const float* bb = (colBase < DIMK) ? bh : bt;
  float* Out            = (colBase < DIMK) ? Eh : Et;
  unsigned short* Outb  = (colBase < DIMK) ? Ehb : Etb;
  const int colOff = colBase & (DIMK - 1);

  const int tx = tid & 15, ty = tid >> 4;
  float acc[8][4];
#pragma unroll
  for (int r = 0; r < 8; ++r)
#pragma unroll
    for (int c = 0; c < 4; ++c) acc[r][c] = 0.f;

  auto stage = [&](int buf, int kt) {
#pragma unroll
    for (int u = 0; u < 4; ++u) {      // A tile: 1024 float4
      const int idx = tid + u * NTHREADS;
      const int r = idx >> 3;
      const int dc = idx & 7;
      const float4 av = *(const float4*)&X[(size_t)(rowBase + r) * DIMK + kt + dc * 4];
      As[buf][dc * 4 + 0][r] = av.x; As[buf][dc * 4 + 1][r] = av.y;
      As[buf][dc * 4 + 2][r] = av.z; As[buf][dc * 4 + 3][r] = av.w;
    }
#pragma unroll
    for (int u = 0; u < 2; ++u) {      // B tile: 512 float4
      const int idx = tid + u * NTHREADS;
      const int r = idx >> 3;
      const int dc = idx & 7;
      const float4 bv = *(const float4*)&W[(size_t)(colOff + r) * DIMK + kt + dc * 4];
      Bs[buf][dc * 4 + 0][r] = bv.x; Bs[buf][dc * 4 + 1][r] = bv.y;
      Bs[buf][dc * 4 + 2][r] = bv.z; Bs[buf][dc * 4 + 3][r] = bv.w;
    }
  };
  auto compute = [&](int buf) {
#pragma unroll 4
    for (int k = 0; k < ETK; ++k) {
      const float4 a0 = *(const float4*)&As[buf][k][ty * 4];
      const float4 a1 = *(const float4*)&As[buf][k][64 + ty * 4];
      const float4 b  = *(const float4*)&Bs[buf][k][tx * 4];
      const float ar[8] = {a0.x, a0.y, a0.z, a0.w, a1.x, a1.y, a1.z, a1.w};
      const float br[4] = {b.x, b.y, b.z, b.w};
#pragma unroll
      for (int r = 0; r < 8; ++r)
#pragma unroll
        for (int c = 0; c < 4; ++c)
          acc[r][c] = fmaf(ar[r], br[c], acc[r][c]);
    }
  };

  stage(0, 0);
  __syncthreads();
#pragma unroll 1
  for (int ki = 0; ki < DIMK / ETK; ki += 2) {
    if (ki + 1 < DIMK / ETK) stage(1, (ki + 1) * ETK);
    compute(0);                  // k ascending -> chain bit-identical
    __syncthreads();
    if (ki + 2 < DIMK / ETK) stage(0, (ki + 2) * ETK);
    compute(1);
    __syncthreads();
  }

  const float4 bv = *(const float4*)&bb[colOff + tx * 4];
  const float br[4] = {bv.x, bv.y, bv.z, bv.w};
#pragma unroll
  for (int r = 0; r < 8; ++r) {
    const int row = rowBase + ((r < 4) ? (ty * 4 + r) : (64 + ty * 4 + r - 4));
    float4 o;
    o.x = acc[r][0] + br[0]; o.y = acc[r][1] + br[1];
    o.z = acc[r][2] + br[2]; o.w = acc[r][3] + br[3];
    const size_t off = (size_t)row * DIMK + colOff + tx * 4;
    *(float4*)&Out[off] = o;
    ushort4 ob;
    ob.x = f2bf(o.x); ob.y = f2bf(o.y); ob.z = f2bf(o.z); ob.w = f2bf(o.w);
    *(ushort4*)&Outb[off] = ob;
  }
}

// ---------------------------------------------------------------------------
// Screen: BYTE-IDENTICAL to round 11 (measured 147 us). Strip structure,
// double-buffered As/Bs, bf16 Csb epilogue, 50 KB LDS -> 3 blocks/CU.
// ---------------------------------------------------------------------------
__global__ __launch_bounds__(256, 3)
void screen_store(const unsigned short* __restrict__ Ehb,
                  const unsigned short* __restrict__ Etb,
                  float* __restrict__ tmax, unsigned short* __restrict__ Sc) {
  __shared__ unsigned short As[2][BM * BK];   // 2 x 8 KB
  __shared__ unsigned short Bs[2][BN * BK];   // 2 x 8 KB
  __shared__ unsigned short Csb[BM * 72];     // 18 KB, stride 72

  const int tid = threadIdx.x;
  const int rowBase = blockIdx.x * BM;
  const int strip = blockIdx.y;
  const int w = tid >> 6, lane = tid & 63;
  const int q = lane >> 4, l15 = lane & 15;
  const int wr = (w & 1) * 64, wc = (w >> 1) * 64;
  const int rr = tid >> 1, hq = tid & 1;   // epilogue: row / 32-col chunk

  const int c0 = tid, c1 = tid + 256;
  const int wb0 = __builtin_amdgcn_readfirstlane(tid & ~63);
  const int wb1 = wb0 + 256;
  const int ar0 = c0 >> 2, ac0 = (c0 & 3) * 8;
  const int ar1 = c1 >> 2, ac1 = (c1 & 3) * 8;

  for (int ct = 0; ct < SCOLS2; ct += BN) {
    const int colBase = strip * SCOLS2 + ct;
    const int tileG = colBase >> 7;          // global 128-col tile index
    f32x4 acc[4][4];
#pragma unroll
    for (int i = 0; i < 4; ++i)
#pragma unroll
      for (int j = 0; j < 4; ++j) acc[i][j] = (f32x4){0.f, 0.f, 0.f, 0.f};

    auto stage = [&](int buf, int kt) {
      gld16(Ehb + (size_t)(rowBase + ar0) * DIMK + kt + ac0, As[buf] + wb0 * 8);
      gld16(Ehb + (size_t)(rowBase + ar1) * DIMK + kt + ac1, As[buf] + wb1 * 8);
      gld16(Etb + (size_t)(colBase + ar0) * DIMK + kt + ac0, Bs[buf] + wb0 * 8);
      gld16(Etb + (size_t)(colBase + ar1) * DIMK + kt + ac1, Bs[buf] + wb1 * 8);
    };
    auto compute = [&](int buf) {
      bf16x8 af[4], bf[4];
#pragma unroll
      for (int i = 0; i < 4; ++i)
        af[i] = *(const bf16x8*)&As[buf][(wr + i * 16 + l15) * BK + q * 8];
#pragma unroll
      for (int j = 0; j < 4; ++j)
        bf[j] = *(const bf16x8*)&Bs[buf][(wc + j * 16 + l15) * BK + q * 8];
#pragma unroll
      for (int i = 0; i < 4; ++i)
#pragma unroll
        for (int j = 0; j < 4; ++j)
          acc[i][j] = __builtin_amdgcn_mfma_f32_16x16x32_bf16(af[i], bf[j], acc[i][j], 0, 0, 0);
    };

    stage(0, 0);
    __syncthreads();
#pragma unroll 1
    for (int ki = 0; ki < DIMK / BK; ki += 2) {
      if (ki + 1 < DIMK / BK) stage(1, (ki + 1) * BK);
      compute(0);
      __syncthreads();
      if (ki + 2 < DIMK / BK) stage(0, (ki + 2) * BK);
      compute(1);
      __syncthreads();
    }

    // Epilogue per 64-col half: bf16 dump -> (chunk max from stored, Sc store).
#pragma unroll
    for (int half = 0; half < 2; ++half) {
      if ((w >> 1) == half) {
#pragma unroll
        for (int i = 0; i < 4; ++i)
#pragma unroll
          for (int j = 0; j < 4; ++j)
#pragma unroll
            for (int rg = 0; rg < 4; ++rg)
              Csb[(wr + i * 16 + q * 4 + rg) * 72 + j * 16 + l15] = f2bf(acc[i][j][rg]);
      }
      __syncthreads();
      float m = -INFINITY;
      uint4 buf4[4];
#pragma unroll
      for (int k = 0; k < 4; ++k) {
        buf4[k] = *(const uint4*)&Csb[rr * 72 + hq * 32 + k * 8];
        const unsigned int uu[4] = {buf4[k].x, buf4[k].y, buf4[k].z, buf4[k].w};
#pragma unroll
        for (int e = 0; e < 4; ++e) {
          m = fmaxf(m, __uint_as_float(uu[e] << 16));
          m = fmaxf(m, __uint_as_float(uu[e] & 0xFFFF0000u));
        }
      }
      tmax[(size_t)(rowBase + rr) * NQ + tileG * 4 + half * 2 + hq] = m;
      uint4* dst = (uint4*)&Sc[(size_t)(rowBase + rr) * NROWS + colBase + half * 64 + hq * 32];
#pragma unroll
      for (int k = 0; k < 4; ++k) dst[k] = buf4[k];
      __syncthreads();   // readback done before next dump overwrites Csb
    }
  }
}

// ---------------------------------------------------------------------------
// Merged tail (r12): wave per row does threshold knockout + Sc scan +
// candidate list in LDS + exact rescore + top-10 + softmax + output.
// All selection/score logic verbatim from round 11's collect_scan /
// rescore_topk -> identical output; removes one launch + the cnt/cand
// global round-trip.
// ---------------------------------------------------------------------------
__global__ __launch_bounds__(256)
void collect_rescore(const unsigned short* __restrict__ Sc,
                     const float* __restrict__ tmax,
                     const float* __restrict__ Eh, const float* __restrict__ Et,
                     float* __restrict__ out) {
  __shared__ int lcnt[4];
  __shared__ int lcand[4][CAP];
  const int lane = threadIdx.x & 63;
  const int wid = threadIdx.x >> 6;
  const int r = blockIdx.x * 4 + wid;

  if (lane == 0) lcnt[wid] = 0;
  __syncthreads();

  // --- threshold: 10 rounds of wave-max knockout over 256 group maxes ---
  const f32x4 gm = *(const f32x4*)&tmax[(size_t)r * NQ + lane * 4];
  float a0 = gm[0], a1 = gm[1], a2 = gm[2], a3 = gm[3];
  float g = -INFINITY;
#pragma unroll 1
  for (int j = 0; j < TOPK; ++j) {
    const float lm = fmaxf(fmaxf(a0, a1), fmaxf(a2, a3));
    g = lm;
#pragma unroll
    for (int off = 32; off > 0; off >>= 1) g = fmaxf(g, __shfl_xor(g, off, 64));
    const unsigned long long ball = __ballot(lm == g);
    const int src = __ffsll((long long)ball) - 1;
    if (lane == src) {
      if      (a0 == g) a0 = -INFINITY;
      else if (a1 == g) a1 = -INFINITY;
      else if (a2 == g) a2 = -INFINITY;
      else              a3 = -INFINITY;
    }
  }
  const float tt = g - TMARGIN;

  // --- scan the stored bf16 logit row; append candidates to LDS ---
  const unsigned short* row = Sc + (size_t)r * NROWS;
#pragma unroll 1
  for (int it = 0; it < NROWS / 512; ++it) {
    const int cc0 = it * 512 + lane * 8;
    const uint4 u = *(const uint4*)&row[cc0];
    const unsigned int uu[4] = {u.x, u.y, u.z, u.w};
#pragma unroll
    for (int e = 0; e < 4; ++e) {
      const float lo = __uint_as_float(uu[e] << 16);
      const float hi = __uint_as_float(uu[e] & 0xFFFF0000u);
      if (lo >= tt) {
        const int p = atomicAdd(&lcnt[wid], 1);
        if (p < CAP) lcand[wid][p] = cc0 + 2 * e;
      }
      if (hi >= tt) {
        const int p = atomicAdd(&lcnt[wid], 1);
        if (p < CAP) lcand[wid][p] = cc0 + 2 * e + 1;
      }
    }
  }
  __syncthreads();   // LDS candidate list complete before rescore reads

  // --- rescore: chain BIT-IDENTICAL to rounds 3-11 ---
  const int n = min(lcnt[wid], CAP);
  const bool active = lane < n;
  const int col = active ? lcand[wid][lane] : 0;

  const float* a = Eh + (size_t)r * DIMK;
  const float* b = Et + (size_t)col * DIMK;
  float p = 0.f;
#pragma unroll 4
  for (int k = 0; k < DIMK; k += 4) {
    const float4 av = *(const float4*)&a[k];
    const float4 bv = *(const float4*)&b[k];
    p = fmaf(av.x, bv.x, p);
    p = fmaf(av.y, bv.y, p);
    p = fmaf(av.z, bv.z, p);
    p = fmaf(av.w, bv.w, p);
  }
  float v = active ? p * SCALE : -INFINITY;
  const int vc = active ? col : 0x7FFFFFFF;

  // 10 rounds of wave-max (tie -> min col); lane j keeps round-j winner.
  float myv = -INFINITY; int myc = 0; float m = 0.f;
  float vv = v; int cc2 = vc;
#pragma unroll 1
  for (int j = 0; j < TOPK; ++j) {
    float bvv = vv; int bcc = cc2;
#pragma unroll
    for (int off = 32; off > 0; off >>= 1) {
      const float ov = __shfl_xor(bvv, off, 64);
      const int oc = __shfl_xor(bcc, off, 64);
      if (ov > bvv || (ov == bvv && oc < bcc)) { bvv = ov; bcc = oc; }
    }
    if (j == 0) m = bvv;
    if (lane == j) { myv = bvv; myc = bcc; }
    if (vv == bvv && cc2 == bcc) vv = -INFINITY;   // knock out (cols unique)
  }

  // softmax: gather the 10 values, sum sequentially (same order as before).
  float sum = 0.f;
#pragma unroll
  for (int j = 0; j < TOPK; ++j) sum += expf(__shfl(myv, j, 64) - m);
  const float inv = 1.0f / sum;

  if (lane < TOPK) {
    const size_t ro = (size_t)r * TOPK + lane;
    out[ro] = (float)r;                                   // src
    out[(size_t)NROWS * TOPK + ro] = (float)myc;          // dst
    out[2 * (size_t)NROWS * TOPK + ro] = expf(myv - m) * inv;  // weight
  }
}

// ---------------------------------------------------------------------------
extern "C" void kernel_launch(void* const* d_in, const int* in_sizes, int n_in,
                              void* d_out, int out_size, void* d_ws, size_t ws_size,
                              hipStream_t stream) {
  const float* X  = (const float*)d_in[0];
  const float* Wh = (const float*)d_in[1];
  const float* bh = (const float*)d_in[2];
  const float* Wt = (const float*)d_in[3];
  const float* bt = (const float*)d_in[4];
  float* out = (float*)d_out;

  char* ws = (char*)d_ws;
  const size_t embB  = (size_t)NROWS * DIMK * sizeof(float);          // 16 MB
  const size_t embBH = (size_t)NROWS * DIMK * sizeof(unsigned short); //  8 MB
  const size_t tmaxB = (size_t)NROWS * NQ * sizeof(float);            //  8 MB
  float* Eh   = (float*)ws;
  float* Et   = (float*)(ws + embB);
  unsigned short* Ehb = (unsigned short*)(ws + 2 * embB);
  unsigned short* Etb = (unsigned short*)(ws + 2 * embB + embBH);
  float* tmax = (float*)(ws + 2 * embB + 2 * embBH);
  unsigned short* Sc = (unsigned short*)(ws + 2 * embB + 2 * embBH + tmaxB);
  // total ws use ~176 MB

  dim3 blk(NTHREADS);
  dim3 g1(NROWS / ETM, (2 * DIMK) / ETN);      // 64 x 16
  embed_gemm<<<g1, blk, 0, stream>>>(X, Wh, bh, Wt, bt, Eh, Et, Ehb, Etb);

  dim3 g2(NROWS / BM, NS2);                    // 64 x 16
  screen_store<<<g2, blk, 0, stream>>>(Ehb, Etb, tmax, Sc);

  collect_rescore<<<NROWS / 4, blk, 0, stream>>>(Sc, tmax, Eh, Et, out);
}

// Round 13
// 381.623 us; speedup vs baseline: 1.3241x; 1.0941x over previous
//
#include <hip/hip_runtime.h>
#include <math.h>

// Problem constants (reference: N=8192, DIM=512, TOPK=10, all fp32)
#define NROWS 8192
#define DIMK  512
#define TOPK  10
#define SCALE 0.044194173824159223f   // fp32(512**-0.5)

// Phase-1 embed GEMM tiling (fp32 VALU): 128x128 tile, 8x8 micro, dbuf.
#define ETM 128
#define ETN 128
#define ETK 32
#define NTHREADS 256

// Screen GEMM tiling (bf16 MFMA) — round-11/12 dbuf strip structure (141 us)
#define BM 128
#define BN 128
#define BK 32
#define NS2 16                    // column strips
#define SCOLS2 (NROWS / NS2)      // 512 cols per strip (4 tiles)
#define NQ 256                    // 32-col groups per row (8192/32)
#define CAP 64                    // max candidates per row
#define TMARGIN 2.0f              // bf16-gemm noise (~0.65) + bf16-storage (~0.35) << 2.0

typedef __attribute__((ext_vector_type(8))) short bf16x8;   // 8 bf16 = 4 VGPRs
typedef __attribute__((ext_vector_type(4))) float f32x4;
typedef __attribute__((ext_vector_type(2))) float f32x2;

__device__ __forceinline__ unsigned short f2bf(float f) {   // RNE fp32->bf16
  unsigned int u = __float_as_uint(f);
  u = (u + 0x7FFF + ((u >> 16) & 1)) >> 16;
  return (unsigned short)u;
}

// async global->LDS, 16B per lane; lds ptr must be wave-uniform base
__device__ __forceinline__ void gld16(const void* g, const void* lds) {
  __builtin_amdgcn_global_load_lds(
      (const __attribute__((address_space(1))) void*)g,
      (__attribute__((address_space(3))) void*)lds, 16, 0, 0);
}

// packed fp32 FMA: two INDEPENDENT exact IEEE fmas (v_pk_fma_f32). Each
// accumulator element's k-chain is unchanged -> bit-identical results.
__device__ __forceinline__ f32x2 pk_fma(f32x2 a, f32x2 b, f32x2 c) {
#if __has_builtin(__builtin_elementwise_fma)
  return __builtin_elementwise_fma(a, b, c);
#else
  f32x2 r; r[0] = fmaf(a[0], b[0], c[0]); r[1] = fmaf(a[1], b[1], c[1]);
  return r;
#endif
}

// ---------------------------------------------------------------------------
// Phase 1: E = X @ W^T + b (fp32 exact) + bf16 copies. r13: 128x128 tile,
// 8x8 micro-tile (0.5 B/FLOP LDS), float2 packed FMA (2x fp32 rate), dbuf
// staging, (256,2) so no spill (r6's 8x8 failed on the 128-VGPR cap).
// Per-element k-chain: sequential ascending fma + bias at end ->
// BIT-IDENTICAL Eh/Et vs rounds 3-12 (rank near-ties depend on it).
// ---------------------------------------------------------------------------
__global__ __launch_bounds__(NTHREADS, 2)
void embed_gemm(const float* __restrict__ X,
                const float* __restrict__ Wh, const float* __restrict__ bh,
                const float* __restrict__ Wt, const float* __restrict__ bt,
                float* __restrict__ Eh, float* __restrict__ Et,
                unsigned short* __restrict__ Ehb, unsigned short* __restrict__ Etb) {
  __shared__ float As[2][ETK][ETM + 4];   // 2 x 16.9 KB, d-major
  __shared__ float Bs[2][ETK][ETN + 4];   // 2 x 16.9 KB

  const int tid = threadIdx.x;
  const int rowBase = blockIdx.x * ETM;
  const int colBase = blockIdx.y * ETN;          // 0..896 over [Wh|Wt]
  const float* W  = (colBase < DIMK) ? Wh : Wt;
  const float* bb = (colBase < DIMK) ? bh : bt;
  float* Out            = (colBase < DIMK) ? Eh : Et;
  unsigned short* Outb  = (colBase < DIMK) ? Ehb : Etb;
  const int colOff = colBase & (DIMK - 1);

  const int tx = tid & 15, ty = tid >> 4;
  // acc2[r][p]: rows r<4 -> ty*4+r, r>=4 -> 64+ty*4+(r-4);
  // pairs p: 0,1 -> cols tx*4+{0,1},{2,3}; 2,3 -> cols 64+tx*4+{0,1},{2,3}.
  f32x2 acc2[8][4];
#pragma unroll
  for (int r = 0; r < 8; ++r)
#pragma unroll
    for (int p = 0; p < 4; ++p) acc2[r][p] = (f32x2){0.f, 0.f};

  auto stage = [&](int buf, int kt) {
#pragma unroll
    for (int u = 0; u < 4; ++u) {      // A tile: 1024 float4
      const int idx = tid + u * NTHREADS;
      const int r = idx >> 3;
      const int dc = idx & 7;
      const float4 av = *(const float4*)&X[(size_t)(rowBase + r) * DIMK + kt + dc * 4];
      As[buf][dc * 4 + 0][r] = av.x; As[buf][dc * 4 + 1][r] = av.y;
      As[buf][dc * 4 + 2][r] = av.z; As[buf][dc * 4 + 3][r] = av.w;
    }
#pragma unroll
    for (int u = 0; u < 4; ++u) {      // B tile: 1024 float4
      const int idx = tid + u * NTHREADS;
      const int r = idx >> 3;
      const int dc = idx & 7;
      const float4 bv = *(const float4*)&W[(size_t)(colOff + r) * DIMK + kt + dc * 4];
      Bs[buf][dc * 4 + 0][r] = bv.x; Bs[buf][dc * 4 + 1][r] = bv.y;
      Bs[buf][dc * 4 + 2][r] = bv.z; Bs[buf][dc * 4 + 3][r] = bv.w;
    }
  };
  auto compute = [&](int buf) {
#pragma unroll 4
    for (int k = 0; k < ETK; ++k) {
      const float4 a0 = *(const float4*)&As[buf][k][ty * 4];
      const float4 a1 = *(const float4*)&As[buf][k][64 + ty * 4];
      const float4 b0 = *(const float4*)&Bs[buf][k][tx * 4];
      const float4 b1 = *(const float4*)&Bs[buf][k][64 + tx * 4];
      const float ar[8] = {a0.x, a0.y, a0.z, a0.w, a1.x, a1.y, a1.z, a1.w};
      const f32x2 bp[4] = {(f32x2){b0.x, b0.y}, (f32x2){b0.z, b0.w},
                           (f32x2){b1.x, b1.y}, (f32x2){b1.z, b1.w}};
#pragma unroll
      for (int r = 0; r < 8; ++r) {
        const f32x2 ar2 = (f32x2){ar[r], ar[r]};
#pragma unroll
        for (int p = 0; p < 4; ++p)
          acc2[r][p] = pk_fma(ar2, bp[p], acc2[r][p]);
      }
    }
  };

  stage(0, 0);
  __syncthreads();
#pragma unroll 1
  for (int ki = 0; ki < DIMK / ETK; ki += 2) {
    if (ki + 1 < DIMK / ETK) stage(1, (ki + 1) * ETK);
    compute(0);                  // k ascending -> chain bit-identical
    __syncthreads();
    if (ki + 2 < DIMK / ETK) stage(0, (ki + 2) * ETK);
    compute(1);
    __syncthreads();
  }

  float br[8];
  {
    const float4 bv0 = *(const float4*)&bb[colOff + tx * 4];
    const float4 bv1 = *(const float4*)&bb[colOff + 64 + tx * 4];
    br[0] = bv0.x; br[1] = bv0.y; br[2] = bv0.z; br[3] = bv0.w;
    br[4] = bv1.x; br[5] = bv1.y; br[6] = bv1.z; br[7] = bv1.w;
  }
#pragma unroll
  for (int r = 0; r < 8; ++r) {
    const int row = rowBase + ((r < 4) ? (ty * 4 + r) : (64 + ty * 4 + r - 4));
    float4 o0, o1;
    o0.x = acc2[r][0][0] + br[0]; o0.y = acc2[r][0][1] + br[1];
    o0.z = acc2[r][1][0] + br[2]; o0.w = acc2[r][1][1] + br[3];
    o1.x = acc2[r][2][0] + br[4]; o1.y = acc2[r][2][1] + br[5];
    o1.z = acc2[r][3][0] + br[6]; o1.w = acc2[r][3][1] + br[7];
    const size_t off0 = (size_t)row * DIMK + colOff + tx * 4;
    const size_t off1 = off0 + 64;
    *(float4*)&Out[off0] = o0;
    *(float4*)&Out[off1] = o1;
    ushort4 q0, q1;
    q0.x = f2bf(o0.x); q0.y = f2bf(o0.y); q0.z = f2bf(o0.z); q0.w = f2bf(o0.w);
    q1.x = f2bf(o1.x); q1.y = f2bf(o1.y); q1.z = f2bf(o1.z); q1.w = f2bf(o1.w);
    *(ushort4*)&Outb[off0] = q0;
    *(ushort4*)&Outb[off1] = q1;
  }
}

// ---------------------------------------------------------------------------
// Screen: BYTE-IDENTICAL to rounds 11/12 (measured 141-147 us). Strip
// structure, double-buffered As/Bs, bf16 Csb epilogue, 50 KB -> 3 blocks/CU.
// ---------------------------------------------------------------------------
__global__ __launch_bounds__(256, 3)
void screen_store(const unsigned short* __restrict__ Ehb,
                  const unsigned short* __restrict__ Etb,
                  float* __restrict__ tmax, unsigned short* __restrict__ Sc) {
  __shared__ unsigned short As[2][BM * BK];   // 2 x 8 KB
  __shared__ unsigned short Bs[2][BN * BK];   // 2 x 8 KB
  __shared__ unsigned short Csb[BM * 72];     // 18 KB, stride 72

  const int tid = threadIdx.x;
  const int rowBase = blockIdx.x * BM;
  const int strip = blockIdx.y;
  const int w = tid >> 6, lane = tid & 63;
  const int q = lane >> 4, l15 = lane & 15;
  const int wr = (w & 1) * 64, wc = (w >> 1) * 64;
  const int rr = tid >> 1, hq = tid & 1;   // epilogue: row / 32-col chunk

  const int c0 = tid, c1 = tid + 256;
  const int wb0 = __builtin_amdgcn_readfirstlane(tid & ~63);
  const int wb1 = wb0 + 256;
  const int ar0 = c0 >> 2, ac0 = (c0 & 3) * 8;
  const int ar1 = c1 >> 2, ac1 = (c1 & 3) * 8;

  for (int ct = 0; ct < SCOLS2; ct += BN) {
    const int colBase = strip * SCOLS2 + ct;
    const int tileG = colBase >> 7;          // global 128-col tile index
    f32x4 acc[4][4];
#pragma unroll
    for (int i = 0; i < 4; ++i)
#pragma unroll
      for (int j = 0; j < 4; ++j) acc[i][j] = (f32x4){0.f, 0.f, 0.f, 0.f};

    auto stage = [&](int buf, int kt) {
      gld16(Ehb + (size_t)(rowBase + ar0) * DIMK + kt + ac0, As[buf] + wb0 * 8);
      gld16(Ehb + (size_t)(rowBase + ar1) * DIMK + kt + ac1, As[buf] + wb1 * 8);
      gld16(Etb + (size_t)(colBase + ar0) * DIMK + kt + ac0, Bs[buf] + wb0 * 8);
      gld16(Etb + (size_t)(colBase + ar1) * DIMK + kt + ac1, Bs[buf] + wb1 * 8);
    };
    auto compute = [&](int buf) {
      bf16x8 af[4], bf[4];
#pragma unroll
      for (int i = 0; i < 4; ++i)
        af[i] = *(const bf16x8*)&As[buf][(wr + i * 16 + l15) * BK + q * 8];
#pragma unroll
      for (int j = 0; j < 4; ++j)
        bf[j] = *(const bf16x8*)&Bs[buf][(wc + j * 16 + l15) * BK + q * 8];
#pragma unroll
      for (int i = 0; i < 4; ++i)
#pragma unroll
        for (int j = 0; j < 4; ++j)
          acc[i][j] = __builtin_amdgcn_mfma_f32_16x16x32_bf16(af[i], bf[j], acc[i][j], 0, 0, 0);
    };

    stage(0, 0);
    __syncthreads();
#pragma unroll 1
    for (int ki = 0; ki < DIMK / BK; ki += 2) {
      if (ki + 1 < DIMK / BK) stage(1, (ki + 1) * BK);
      compute(0);
      __syncthreads();
      if (ki + 2 < DIMK / BK) stage(0, (ki + 2) * BK);
      compute(1);
      __syncthreads();
    }

    // Epilogue per 64-col half: bf16 dump -> (chunk max from stored, Sc store).
#pragma unroll
    for (int half = 0; half < 2; ++half) {
      if ((w >> 1) == half) {
#pragma unroll
        for (int i = 0; i < 4; ++i)
#pragma unroll
          for (int j = 0; j < 4; ++j)
#pragma unroll
            for (int rg = 0; rg < 4; ++rg)
              Csb[(wr + i * 16 + q * 4 + rg) * 72 + j * 16 + l15] = f2bf(acc[i][j][rg]);
      }
      __syncthreads();
      float m = -INFINITY;
      uint4 buf4[4];
#pragma unroll
      for (int k = 0; k < 4; ++k) {
        buf4[k] = *(const uint4*)&Csb[rr * 72 + hq * 32 + k * 8];
        const unsigned int uu[4] = {buf4[k].x, buf4[k].y, buf4[k].z, buf4[k].w};
#pragma unroll
        for (int e = 0; e < 4; ++e) {
          m = fmaxf(m, __uint_as_float(uu[e] << 16));
          m = fmaxf(m, __uint_as_float(uu[e] & 0xFFFF0000u));
        }
      }
      tmax[(size_t)(rowBase + rr) * NQ + tileG * 4 + half * 2 + hq] = m;
      uint4* dst = (uint4*)&Sc[(size_t)(rowBase + rr) * NROWS + colBase + half * 64 + hq * 32];
#pragma unroll
      for (int k = 0; k < 4; ++k) dst[k] = buf4[k];
      __syncthreads();   // readback done before next dump overwrites Csb
    }
  }
}

// ---------------------------------------------------------------------------
// Merged tail r13: BLOCK per row. All 4 waves: redundant threshold knockout
// (identical tt) then scan one quarter of the stored bf16 row each into a
// shared LDS candidate list (4x shorter latency chain, 4x block count).
// Wave 0: exact rescore (chain BIT-IDENTICAL to rounds 3-12) + top-10 +
// softmax + output, logic verbatim from round 12. Candidate-list ORDER
// differs from r12 but selection is value+min-col deterministic and softmax
// sums in rank order -> output invariant.
// ---------------------------------------------------------------------------
__global__ __launch_bounds__(256)
void collect_rescore(const unsigned short* __restrict__ Sc,
                     const float* __restrict__ tmax,
                     const float* __restrict__ Eh, const float* __restrict__ Et,
                     float* __restrict__ out) {
  __shared__ int lcnt;
  __shared__ int lcand[CAP];
  const int lane = threadIdx.x & 63;
  const int wid = threadIdx.x >> 6;
  const int r = blockIdx.x;

  if (threadIdx.x == 0) lcnt = 0;
  __syncthreads();

  // --- threshold: 10 rounds of wave-max knockout over 256 group maxes ---
  const f32x4 gm = *(const f32x4*)&tmax[(size_t)r * NQ + lane * 4];
  float a0 = gm[0], a1 = gm[1], a2 = gm[2], a3 = gm[3];
  float g = -INFINITY;
#pragma unroll 1
  for (int j = 0; j < TOPK; ++j) {
    const float lm = fmaxf(fmaxf(a0, a1), fmaxf(a2, a3));
    g = lm;
#pragma unroll
    for (int off = 32; off > 0; off >>= 1) g = fmaxf(g, __shfl_xor(g, off, 64));
    const unsigned long long ball = __ballot(lm == g);
    const int src = __ffsll((long long)ball) - 1;
    if (lane == src) {
      if      (a0 == g) a0 = -INFINITY;
      else if (a1 == g) a1 = -INFINITY;
      else if (a2 == g) a2 = -INFINITY;
      else              a3 = -INFINITY;
    }
  }
  const float tt = g - TMARGIN;

  // --- scan: wave wid covers columns [wid*2048, (wid+1)*2048) ---
  const unsigned short* row = Sc + (size_t)r * NROWS;
#pragma unroll 1
  for (int it = 0; it < 4; ++it) {
    const int cc0 = (wid * 4 + it) * 512 + lane * 8;
    const uint4 u = *(const uint4*)&row[cc0];
    const unsigned int uu[4] = {u.x, u.y, u.z, u.w};
#pragma unroll
    for (int e = 0; e < 4; ++e) {
      const float lo = __uint_as_float(uu[e] << 16);
      const float hi = __uint_as_float(uu[e] & 0xFFFF0000u);
      if (lo >= tt) {
        const int p = atomicAdd(&lcnt, 1);
        if (p < CAP) lcand[p] = cc0 + 2 * e;
      }
      if (hi >= tt) {
        const int p = atomicAdd(&lcnt, 1);
        if (p < CAP) lcand[p] = cc0 + 2 * e + 1;
      }
    }
  }
  __syncthreads();   // candidate list complete
  if (wid != 0) return;

  // --- rescore on wave 0: chain BIT-IDENTICAL to rounds 3-12 ---
  const int n = min(lcnt, CAP);
  const bool active = lane < n;
  const int col = active ? lcand[lane] : 0;

  const float* a = Eh + (size_t)r * DIMK;
  const float* b = Et + (size_t)col * DIMK;
  float p = 0.f;
#pragma unroll 4
  for (int k = 0; k < DIMK; k += 4) {
    const float4 av = *(const float4*)&a[k];
    const float4 bv = *(const float4*)&b[k];
    p = fmaf(av.x, bv.x, p);
    p = fmaf(av.y, bv.y, p);
    p = fmaf(av.z, bv.z, p);
    p = fmaf(av.w, bv.w, p);
  }
  float v = active ? p * SCALE : -INFINITY;
  const int vc = active ? col : 0x7FFFFFFF;

  // 10 rounds of wave-max (tie -> min col); lane j keeps round-j winner.
  float myv = -INFINITY; int myc = 0; float m = 0.f;
  float vv = v; int cc2 = vc;
#pragma unroll 1
  for (int j = 0; j < TOPK; ++j) {
    float bvv = vv; int bcc = cc2;
#pragma unroll
    for (int off = 32; off > 0; off >>= 1) {
      const float ov = __shfl_xor(bvv, off, 64);
      const int oc = __shfl_xor(bcc, off, 64);
      if (ov > bvv || (ov == bvv && oc < bcc)) { bvv = ov; bcc = oc; }
    }
    if (j == 0) m = bvv;
    if (lane == j) { myv = bvv; myc = bcc; }
    if (vv == bvv && cc2 == bcc) vv = -INFINITY;   // knock out (cols unique)
  }

  // softmax: gather the 10 values, sum sequentially (rank order, as before).
  float sum = 0.f;
#pragma unroll
  for (int j = 0; j < TOPK; ++j) sum += expf(__shfl(myv, j, 64) - m);
  const float inv = 1.0f / sum;

  if (lane < TOPK) {
    const size_t ro = (size_t)r * TOPK + lane;
    out[ro] = (float)r;                                   // src
    out[(size_t)NROWS * TOPK + ro] = (float)myc;          // dst
    out[2 * (size_t)NROWS * TOPK + ro] = expf(myv - m) * inv;  // weight
  }
}

// ---------------------------------------------------------------------------
extern "C" void kernel_launch(void* const* d_in, const int* in_sizes, int n_in,
                              void* d_out, int out_size, void* d_ws, size_t ws_size,
                              hipStream_t stream) {
  const float* X  = (const float*)d_in[0];
  const float* Wh = (const float*)d_in[1];
  const float* bh = (const float*)d_in[2];
  const float* Wt = (const float*)d_in[3];
  const float* bt = (const float*)d_in[4];
  float* out = (float*)d_out;

  char* ws = (char*)d_ws;
  const size_t embB  = (size_t)NROWS * DIMK * sizeof(float);          // 16 MB
  const size_t embBH = (size_t)NROWS * DIMK * sizeof(unsigned short); //  8 MB
  const size_t tmaxB = (size_t)NROWS * NQ * sizeof(float);            //  8 MB
  float* Eh   = (float*)ws;
  float* Et   = (float*)(ws + embB);
  unsigned short* Ehb = (unsigned short*)(ws + 2 * embB);
  unsigned short* Etb = (unsigned short*)(ws + 2 * embB + embBH);
  float* tmax = (float*)(ws + 2 * embB + 2 * embBH);
  unsigned short* Sc = (unsigned short*)(ws + 2 * embB + 2 * embBH + tmaxB);
  // total ws use ~176 MB

  dim3 blk(NTHREADS);
  dim3 g1(NROWS / ETM, (2 * DIMK) / ETN);      // 64 x 8
  embed_gemm<<<g1, blk, 0, stream>>>(X, Wh, bh, Wt, bt, Eh, Et, Ehb, Etb);

  dim3 g2(NROWS / BM, NS2);                    // 64 x 16
  screen_store<<<g2, blk, 0, stream>>>(Ehb, Etb, tmax, Sc);

  collect_rescore<<<NROWS, blk, 0, stream>>>(Sc, tmax, Eh, Et, out);
}

// Round 14
// 368.708 us; speedup vs baseline: 1.3705x; 1.0350x over previous
//
#include <hip/hip_runtime.h>
#include <math.h>

// Problem constants (reference: N=8192, DIM=512, TOPK=10, all fp32)
#define NROWS 8192
#define DIMK  512
#define TOPK  10
#define SCALE 0.044194173824159223f   // fp32(512**-0.5)

// Phase-1 embed GEMM tiling (fp32 VALU): 128x128 tile, 8x8 micro, dbuf.
#define ETM 128
#define ETN 128
#define ETK 32
#define NTHREADS 256

// Screen GEMM tiling (bf16 MFMA): r14 = BN 256 (32 MFMA/wave per barrier)
#define BM 128
#define BN 256
#define BK 32
#define NS2 8                     // column strips
#define SCOLS2 (NROWS / NS2)      // 1024 cols per strip (4 tiles of 256)
#define NQ 256                    // 32-col groups per row (8192/32)
#define CAP 64                    // max candidates per row
#define TMARGIN 2.0f              // bf16-gemm noise (~0.65) + bf16-storage (~0.35) << 2.0

typedef __attribute__((ext_vector_type(8))) short bf16x8;   // 8 bf16 = 4 VGPRs
typedef __attribute__((ext_vector_type(4))) float f32x4;
typedef __attribute__((ext_vector_type(2))) float f32x2;

__device__ __forceinline__ unsigned short f2bf(float f) {   // RNE fp32->bf16
  unsigned int u = __float_as_uint(f);
  u = (u + 0x7FFF + ((u >> 16) & 1)) >> 16;
  return (unsigned short)u;
}

// async global->LDS, 16B per lane; lds ptr must be wave-uniform base
__device__ __forceinline__ void gld16(const void* g, const void* lds) {
  __builtin_amdgcn_global_load_lds(
      (const __attribute__((address_space(1))) void*)g,
      (__attribute__((address_space(3))) void*)lds, 16, 0, 0);
}

// packed fp32 FMA: two INDEPENDENT exact IEEE fmas (v_pk_fma_f32). Each
// accumulator element's k-chain is unchanged -> bit-identical results.
__device__ __forceinline__ f32x2 pk_fma(f32x2 a, f32x2 b, f32x2 c) {
#if __has_builtin(__builtin_elementwise_fma)
  return __builtin_elementwise_fma(a, b, c);
#else
  f32x2 r; r[0] = fmaf(a[0], b[0], c[0]); r[1] = fmaf(a[1], b[1], c[1]);
  return r;
#endif
}

// ---------------------------------------------------------------------------
// Phase 1 (byte-identical to r13, measured good): E = X @ W^T + b + bf16
// copies. 128x128 tile, 8x8 micro, packed FMA, dbuf. Per-element k-chain:
// sequential ascending fma + bias at end -> BIT-IDENTICAL Eh/Et vs r3-13.
// ---------------------------------------------------------------------------
__global__ __launch_bounds__(NTHREADS, 2)
void embed_gemm(const float* __restrict__ X,
                const float* __restrict__ Wh, const float* __restrict__ bh,
                const float* __restrict__ Wt, const float* __restrict__ bt,
                float* __restrict__ Eh, float* __restrict__ Et,
                unsigned short* __restrict__ Ehb, unsigned short* __restrict__ Etb) {
  __shared__ float As[2][ETK][ETM + 4];   // 2 x 16.9 KB, d-major
  __shared__ float Bs[2][ETK][ETN + 4];   // 2 x 16.9 KB

  const int tid = threadIdx.x;
  const int rowBase = blockIdx.x * ETM;
  const int colBase = blockIdx.y * ETN;          // 0..896 over [Wh|Wt]
  const float* W  = (colBase < DIMK) ? Wh : Wt;
  const float* bb = (colBase < DIMK) ? bh : bt;
  float* Out            = (colBase < DIMK) ? Eh : Et;
  unsigned short* Outb  = (colBase < DIMK) ? Ehb : Etb;
  const int colOff = colBase & (DIMK - 1);

  const int tx = tid & 15, ty = tid >> 4;
  f32x2 acc2[8][4];
#pragma unroll
  for (int r = 0; r < 8; ++r)
#pragma unroll
    for (int p = 0; p < 4; ++p) acc2[r][p] = (f32x2){0.f, 0.f};

  auto stage = [&](int buf, int kt) {
#pragma unroll
    for (int u = 0; u < 4; ++u) {      // A tile: 1024 float4
      const int idx = tid + u * NTHREADS;
      const int r = idx >> 3;
      const int dc = idx & 7;
      const float4 av = *(const float4*)&X[(size_t)(rowBase + r) * DIMK + kt + dc * 4];
      As[buf][dc * 4 + 0][r] = av.x; As[buf][dc * 4 + 1][r] = av.y;
      As[buf][dc * 4 + 2][r] = av.z; As[buf][dc * 4 + 3][r] = av.w;
    }
#pragma unroll
    for (int u = 0; u < 4; ++u) {      // B tile: 1024 float4
      const int idx = tid + u * NTHREADS;
      const int r = idx >> 3;
      const int dc = idx & 7;
      const float4 bv = *(const float4*)&W[(size_t)(colOff + r) * DIMK + kt + dc * 4];
      Bs[buf][dc * 4 + 0][r] = bv.x; Bs[buf][dc * 4 + 1][r] = bv.y;
      Bs[buf][dc * 4 + 2][r] = bv.z; Bs[buf][dc * 4 + 3][r] = bv.w;
    }
  };
  auto compute = [&](int buf) {
#pragma unroll 4
    for (int k = 0; k < ETK; ++k) {
      const float4 a0 = *(const float4*)&As[buf][k][ty * 4];
      const float4 a1 = *(const float4*)&As[buf][k][64 + ty * 4];
      const float4 b0 = *(const float4*)&Bs[buf][k][tx * 4];
      const float4 b1 = *(const float4*)&Bs[buf][k][64 + tx * 4];
      const float ar[8] = {a0.x, a0.y, a0.z, a0.w, a1.x, a1.y, a1.z, a1.w};
      const f32x2 bp[4] = {(f32x2){b0.x, b0.y}, (f32x2){b0.z, b0.w},
                           (f32x2){b1.x, b1.y}, (f32x2){b1.z, b1.w}};
#pragma unroll
      for (int r = 0; r < 8; ++r) {
        const f32x2 ar2 = (f32x2){ar[r], ar[r]};
#pragma unroll
        for (int p = 0; p < 4; ++p)
          acc2[r][p] = pk_fma(ar2, bp[p], acc2[r][p]);
      }
    }
  };

  stage(0, 0);
  __syncthreads();
#pragma unroll 1
  for (int ki = 0; ki < DIMK / ETK; ki += 2) {
    if (ki + 1 < DIMK / ETK) stage(1, (ki + 1) * ETK);
    compute(0);                  // k ascending -> chain bit-identical
    __syncthreads();
    if (ki + 2 < DIMK / ETK) stage(0, (ki + 2) * ETK);
    compute(1);
    __syncthreads();
  }

  float br[8];
  {
    const float4 bv0 = *(const float4*)&bb[colOff + tx * 4];
    const float4 bv1 = *(const float4*)&bb[colOff + 64 + tx * 4];
    br[0] = bv0.x; br[1] = bv0.y; br[2] = bv0.z; br[3] = bv0.w;
    br[4] = bv1.x; br[5] = bv1.y; br[6] = bv1.z; br[7] = bv1.w;
  }
#pragma unroll
  for (int r = 0; r < 8; ++r) {
    const int row = rowBase + ((r < 4) ? (ty * 4 + r) : (64 + ty * 4 + r - 4));
    float4 o0, o1;
    o0.x = acc2[r][0][0] + br[0]; o0.y = acc2[r][0][1] + br[1];
    o0.z = acc2[r][1][0] + br[2]; o0.w = acc2[r][1][1] + br[3];
    o1.x = acc2[r][2][0] + br[4]; o1.y = acc2[r][2][1] + br[5];
    o1.z = acc2[r][3][0] + br[6]; o1.w = acc2[r][3][1] + br[7];
    const size_t off0 = (size_t)row * DIMK + colOff + tx * 4;
    const size_t off1 = off0 + 64;
    *(float4*)&Out[off0] = o0;
    *(float4*)&Out[off1] = o1;
    ushort4 q0, q1;
    q0.x = f2bf(o0.x); q0.y = f2bf(o0.y); q0.z = f2bf(o0.z); q0.w = f2bf(o0.w);
    q1.x = f2bf(o1.x); q1.y = f2bf(o1.y); q1.z = f2bf(o1.z); q1.w = f2bf(o1.w);
    *(ushort4*)&Outb[off0] = q0;
    *(ushort4*)&Outb[off1] = q1;
  }
}

// ---------------------------------------------------------------------------
// Screen r14: BN=256 per block -> 32 MFMA/wave between barriers (2x r13's
// work/barrier ratio; MfmaUtil was 19% with only 16 MFMA/~77cy per drain).
// Wave grid 2x2: wr=(w&1)*64 rows, wc=(w>>1)*128 cols; acc[4][8] (128 VGPR,
// under the (256,2) cap). dbuf staging kept. Epilogue = 4x 64-col quarters,
// code per quarter identical to r13's per-half (Csb 18 KB, chunk max from
// stored bf16, line-granular Sc writes; tmax group formula unchanged).
// LDS 16+32+18 = 66 KB -> 2 blocks/CU; grid 64x8 = 512 = 2x256 CUs.
// Per-(row,col) MFMA chain is the same ascending-kt sequence -> acc
// BIT-IDENTICAL -> tmax/threshold/candidates/output unchanged.
// ---------------------------------------------------------------------------
__global__ __launch_bounds__(256, 2)
void screen_store(const unsigned short* __restrict__ Ehb,
                  const unsigned short* __restrict__ Etb,
                  float* __restrict__ tmax, unsigned short* __restrict__ Sc) {
  __shared__ unsigned short As[2][BM * BK];   // 2 x 8 KB
  __shared__ unsigned short Bs[2][BN * BK];   // 2 x 16 KB
  __shared__ unsigned short Csb[BM * 72];     // 18 KB, stride 72

  const int tid = threadIdx.x;
  const int rowBase = blockIdx.x * BM;
  const int strip = blockIdx.y;
  const int w = tid >> 6, lane = tid & 63;
  const int q = lane >> 4, l15 = lane & 15;
  const int wr = (w & 1) * 64, wc = (w >> 1) * 128;
  const int rr = tid >> 1, hq = tid & 1;   // epilogue: row / 32-col chunk

  const int wb0 = __builtin_amdgcn_readfirstlane(tid & ~63);
  // A: 512 chunks (2/thread); B: 1024 chunks (4/thread); chunk c -> row c>>2,
  // k-off (c&3)*8; LDS dest = wave-uniform base + lane*16 (gld constraint).
  const int ar0 = tid >> 2,        ac0 = (tid & 3) * 8;
  const int ar1 = (tid + 256) >> 2, ac1 = ((tid + 256) & 3) * 8;

  for (int ct = 0; ct < SCOLS2; ct += BN) {
    const int colBase = strip * SCOLS2 + ct;
    f32x4 acc[4][8];
#pragma unroll
    for (int i = 0; i < 4; ++i)
#pragma unroll
      for (int j = 0; j < 8; ++j) acc[i][j] = (f32x4){0.f, 0.f, 0.f, 0.f};

    auto stage = [&](int buf, int kt) {
      gld16(Ehb + (size_t)(rowBase + ar0) * DIMK + kt + ac0, As[buf] + wb0 * 8);
      gld16(Ehb + (size_t)(rowBase + ar1) * DIMK + kt + ac1, As[buf] + (wb0 + 256) * 8);
#pragma unroll
      for (int u = 0; u < 4; ++u) {
        const int c = tid + u * 256;
        gld16(Etb + (size_t)(colBase + (c >> 2)) * DIMK + kt + (c & 3) * 8,
              Bs[buf] + (wb0 + u * 256) * 8);
      }
    };
    auto compute = [&](int buf) {
      bf16x8 af[4], bf[8];
#pragma unroll
      for (int i = 0; i < 4; ++i)
        af[i] = *(const bf16x8*)&As[buf][(wr + i * 16 + l15) * BK + q * 8];
#pragma unroll
      for (int j = 0; j < 8; ++j)
        bf[j] = *(const bf16x8*)&Bs[buf][(wc + j * 16 + l15) * BK + q * 8];
#pragma unroll
      for (int i = 0; i < 4; ++i)
#pragma unroll
        for (int j = 0; j < 8; ++j)
          acc[i][j] = __builtin_amdgcn_mfma_f32_16x16x32_bf16(af[i], bf[j], acc[i][j], 0, 0, 0);
    };

    stage(0, 0);
    __syncthreads();
#pragma unroll 1
    for (int ki = 0; ki < DIMK / BK; ki += 2) {
      if (ki + 1 < DIMK / BK) stage(1, (ki + 1) * BK);
      compute(0);
      __syncthreads();
      if (ki + 2 < DIMK / BK) stage(0, (ki + 2) * BK);
      compute(1);
      __syncthreads();
    }

    // Epilogue: 4 quarters of 64 cols; per quarter identical to r13's half.
#pragma unroll
    for (int qtr = 0; qtr < 4; ++qtr) {
      const int jbase = (qtr & 1) * 4;
      if ((w >> 1) == (qtr >> 1)) {
#pragma unroll
        for (int i = 0; i < 4; ++i)
#pragma unroll
          for (int jj = 0; jj < 4; ++jj)
#pragma unroll
            for (int rg = 0; rg < 4; ++rg)
              Csb[(wr + i * 16 + q * 4 + rg) * 72 + jj * 16 + l15] =
                  f2bf(acc[i][jbase + jj][rg]);
      }
      __syncthreads();
      float m = -INFINITY;
      uint4 buf4[4];
#pragma unroll
      for (int k = 0; k < 4; ++k) {
        buf4[k] = *(const uint4*)&Csb[rr * 72 + hq * 32 + k * 8];
        const unsigned int uu[4] = {buf4[k].x, buf4[k].y, buf4[k].z, buf4[k].w};
#pragma unroll
        for (int e = 0; e < 4; ++e) {
          m = fmaxf(m, __uint_as_float(uu[e] << 16));
          m = fmaxf(m, __uint_as_float(uu[e] & 0xFFFF0000u));
        }
      }
      const int gbase = (colBase + qtr * 64) >> 5;   // global 32-col group
      tmax[(size_t)(rowBase + rr) * NQ + gbase + hq] = m;
      uint4* dst = (uint4*)&Sc[(size_t)(rowBase + rr) * NROWS + colBase + qtr * 64 + hq * 32];
#pragma unroll
      for (int k = 0; k < 4; ++k) dst[k] = buf4[k];
      __syncthreads();   // readback done before next dump overwrites Csb
    }
  }
}

// ---------------------------------------------------------------------------
// Merged tail (byte-identical to r13): BLOCK per row; 4 waves scan quarters
// into shared LDS candidate list; wave 0 rescores (chain BIT-IDENTICAL to
// r3-13) + top-10 + softmax + output.
// ---------------------------------------------------------------------------
__global__ __launch_bounds__(256)
void collect_rescore(const unsigned short* __restrict__ Sc,
                     const float* __restrict__ tmax,
                     const float* __restrict__ Eh, const float* __restrict__ Et,
                     float* __restrict__ out) {
  __shared__ int lcnt;
  __shared__ int lcand[CAP];
  const int lane = threadIdx.x & 63;
  const int wid = threadIdx.x >> 6;
  const int r = blockIdx.x;

  if (threadIdx.x == 0) lcnt = 0;
  __syncthreads();

  // --- threshold: 10 rounds of wave-max knockout over 256 group maxes ---
  const f32x4 gm = *(const f32x4*)&tmax[(size_t)r * NQ + lane * 4];
  float a0 = gm[0], a1 = gm[1], a2 = gm[2], a3 = gm[3];
  float g = -INFINITY;
#pragma unroll 1
  for (int j = 0; j < TOPK; ++j) {
    const float lm = fmaxf(fmaxf(a0, a1), fmaxf(a2, a3));
    g = lm;
#pragma unroll
    for (int off = 32; off > 0; off >>= 1) g = fmaxf(g, __shfl_xor(g, off, 64));
    const unsigned long long ball = __ballot(lm == g);
    const int src = __ffsll((long long)ball) - 1;
    if (lane == src) {
      if      (a0 == g) a0 = -INFINITY;
      else if (a1 == g) a1 = -INFINITY;
      else if (a2 == g) a2 = -INFINITY;
      else              a3 = -INFINITY;
    }
  }
  const float tt = g - TMARGIN;

  // --- scan: wave wid covers columns [wid*2048, (wid+1)*2048) ---
  const unsigned short* row = Sc + (size_t)r * NROWS;
#pragma unroll 1
  for (int it = 0; it < 4; ++it) {
    const int cc0 = (wid * 4 + it) * 512 + lane * 8;
    const uint4 u = *(const uint4*)&row[cc0];
    const unsigned int uu[4] = {u.x, u.y, u.z, u.w};
#pragma unroll
    for (int e = 0; e < 4; ++e) {
      const float lo = __uint_as_float(uu[e] << 16);
      const float hi = __uint_as_float(uu[e] & 0xFFFF0000u);
      if (lo >= tt) {
        const int p = atomicAdd(&lcnt, 1);
        if (p < CAP) lcand[p] = cc0 + 2 * e;
      }
      if (hi >= tt) {
        const int p = atomicAdd(&lcnt, 1);
        if (p < CAP) lcand[p] = cc0 + 2 * e + 1;
      }
    }
  }
  __syncthreads();   // candidate list complete
  if (wid != 0) return;

  // --- rescore on wave 0: chain BIT-IDENTICAL to rounds 3-13 ---
  const int n = min(lcnt, CAP);
  const bool active = lane < n;
  const int col = active ? lcand[lane] : 0;

  const float* a = Eh + (size_t)r * DIMK;
  const float* b = Et + (size_t)col * DIMK;
  float p = 0.f;
#pragma unroll 4
  for (int k = 0; k < DIMK; k += 4) {
    const float4 av = *(const float4*)&a[k];
    const float4 bv = *(const float4*)&b[k];
    p = fmaf(av.x, bv.x, p);
    p = fmaf(av.y, bv.y, p);
    p = fmaf(av.z, bv.z, p);
    p = fmaf(av.w, bv.w, p);
  }
  float v = active ? p * SCALE : -INFINITY;
  const int vc = active ? col : 0x7FFFFFFF;

  // 10 rounds of wave-max (tie -> min col); lane j keeps round-j winner.
  float myv = -INFINITY; int myc = 0; float m = 0.f;
  float vv = v; int cc2 = vc;
#pragma unroll 1
  for (int j = 0; j < TOPK; ++j) {
    float bvv = vv; int bcc = cc2;
#pragma unroll
    for (int off = 32; off > 0; off >>= 1) {
      const float ov = __shfl_xor(bvv, off, 64);
      const int oc = __shfl_xor(bcc, off, 64);
      if (ov > bvv || (ov == bvv && oc < bcc)) { bvv = ov; bcc = oc; }
    }
    if (j == 0) m = bvv;
    if (lane == j) { myv = bvv; myc = bcc; }
    if (vv == bvv && cc2 == bcc) vv = -INFINITY;   // knock out (cols unique)
  }

  // softmax: gather the 10 values, sum sequentially (rank order, as before).
  float sum = 0.f;
#pragma unroll
  for (int j = 0; j < TOPK; ++j) sum += expf(__shfl(myv, j, 64) - m);
  const float inv = 1.0f / sum;

  if (lane < TOPK) {
    const size_t ro = (size_t)r * TOPK + lane;
    out[ro] = (float)r;                                   // src
    out[(size_t)NROWS * TOPK + ro] = (float)myc;          // dst
    out[2 * (size_t)NROWS * TOPK + ro] = expf(myv - m) * inv;  // weight
  }
}

// ---------------------------------------------------------------------------
extern "C" void kernel_launch(void* const* d_in, const int* in_sizes, int n_in,
                              void* d_out, int out_size, void* d_ws, size_t ws_size,
                              hipStream_t stream) {
  const float* X  = (const float*)d_in[0];
  const float* Wh = (const float*)d_in[1];
  const float* bh = (const float*)d_in[2];
  const float* Wt = (const float*)d_in[3];
  const float* bt = (const float*)d_in[4];
  float* out = (float*)d_out;

  char* ws = (char*)d_ws;
  const size_t embB  = (size_t)NROWS * DIMK * sizeof(float);          // 16 MB
  const size_t embBH = (size_t)NROWS * DIMK * sizeof(unsigned short); //  8 MB
  const size_t tmaxB = (size_t)NROWS * NQ * sizeof(float);            //  8 MB
  float* Eh   = (float*)ws;
  float* Et   = (float*)(ws + embB);
  unsigned short* Ehb = (unsigned short*)(ws + 2 * embB);
  unsigned short* Etb = (unsigned short*)(ws + 2 * embB + embBH);
  float* tmax = (float*)(ws + 2 * embB + 2 * embBH);
  unsigned short* Sc = (unsigned short*)(ws + 2 * embB + 2 * embBH + tmaxB);
  // total ws use ~176 MB

  dim3 blk(NTHREADS);
  dim3 g1(NROWS / ETM, (2 * DIMK) / ETN);      // 64 x 8
  embed_gemm<<<g1, blk, 0, stream>>>(X, Wh, bh, Wt, bt, Eh, Et, Ehb, Etb);

  dim3 g2(NROWS / BM, NS2);                    // 64 x 8
  screen_store<<<g2, blk, 0, stream>>>(Ehb, Etb, tmax, Sc);

  collect_rescore<<<NROWS, blk, 0, stream>>>(Sc, tmax, Eh, Et, out);
}